// Round 6
// baseline (1447.246 us; speedup 1.0000x reference)
//
#include <hip/hip_runtime.h>
#include <math.h>

// HGSA: 3x (mask-guided channel-attention MSA + LN + convFFN) on [2,64,256,256].
// External I/O fp32. Internal activations bf16, residual stream X fp32 (+bf16
// mirror Xb), weights bf16 in LDS.
// R5: MFMA gemms (16x64 tile/wave). R6: attn_partial rewrite (1024 blocks,
// full-channel staged tiles, 4 syncs); FFN un-chunked (64->256->64, one X RMW);
// QKV fused into one kernel. FFN 256-ch temps alias dead 64-ch buffers.

typedef unsigned short bhalf;
typedef unsigned int u32;
typedef __attribute__((ext_vector_type(8))) short bf16x8;
typedef __attribute__((ext_vector_type(4))) float f32x4;

#define GEMM_GRID 2048      // 131072 rows / 64 rows per block
#define LN_GRID 2048

__device__ __forceinline__ float bf2f(bhalf b) {
  union { u32 u; float f; } c; c.u = ((u32)b) << 16; return c.f;
}
__device__ __forceinline__ bhalf f2bf(float f) {
  union { float f; u32 u; } c; c.f = f;
  u32 lsb = (c.u >> 16) & 1u;
  c.u += 0x7fffu + lsb;           // round-to-nearest-even
  return (bhalf)(c.u >> 16);
}
__device__ __forceinline__ u32 pack2bf(float a, float b) {
  return (u32)f2bf(a) | ((u32)f2bf(b) << 16);
}
__device__ __forceinline__ void unpack2(u32 p, float& a, float& b) {
  union { u32 u; float f; } c0, c1;
  c0.u = p << 16; c1.u = p & 0xffff0000u;
  a = c0.f; b = c1.f;
}
__device__ __forceinline__ void unpack8(uint4 u, float* f) {
  unpack2(u.x, f[0], f[1]); unpack2(u.y, f[2], f[3]);
  unpack2(u.z, f[4], f[5]); unpack2(u.w, f[6], f[7]);
}
__device__ __forceinline__ float gelu_f(float v) {   // exact gelu
  return 0.5f * v * (1.0f + erff(v * 0.70710678118654752440f));
}
__device__ __forceinline__ uint4 pack16(const float* v) {
  uint4 s;
  s.x = pack2bf(v[0], v[1]); s.y = pack2bf(v[2], v[3]);
  s.z = pack2bf(v[4], v[5]); s.w = pack2bf(v[6], v[7]);
  return s;
}

// ---------------- transposes ----------------
template<int MODE>   // 0: x -> fp32 X AND bf16 Xb.  1: mask -> bf16 only.
__global__ __launch_bounds__(256) void nchw2nhwc(const float* __restrict__ in,
                                                 void* __restrict__ out,
                                                 bhalf* __restrict__ out2) {
  __shared__ float tile[64][65];
  int t = threadIdx.x;
  int b = blockIdx.x >> 10;
  int n0 = (blockIdx.x & 1023) << 6;
  #pragma unroll
  for (int j = 0; j < 16; ++j) {
    int idx = j * 256 + t;
    int c = idx >> 6, nn = idx & 63;
    tile[c][nn] = in[(((size_t)(b * 64 + c)) << 16) + n0 + nn];
  }
  __syncthreads();
  #pragma unroll
  for (int j = 0; j < 16; ++j) {
    int idx = j * 256 + t;
    int nn = idx >> 6, c = idx & 63;
    size_t o = ((((size_t)b << 16) + n0 + nn) << 6) + c;
    float v = tile[c][nn];
    if (MODE == 0) { ((float*)out)[o] = v; out2[o] = f2bf(v); }
    else           { ((bhalf*)out)[o] = f2bf(v); }
  }
}

__global__ __launch_bounds__(256) void nhwc2nchw(const float* __restrict__ in,
                                                 float* __restrict__ out) {
  __shared__ float tile[64][65];
  int t = threadIdx.x;
  int b = blockIdx.x >> 10;
  int n0 = (blockIdx.x & 1023) << 6;
  #pragma unroll
  for (int j = 0; j < 16; ++j) {
    int idx = j * 256 + t;
    int nn = idx >> 6, c = idx & 63;
    tile[c][nn] = in[((((size_t)b << 16) + n0 + nn) << 6) + c];
  }
  __syncthreads();
  #pragma unroll
  for (int j = 0; j < 16; ++j) {
    int idx = j * 256 + t;
    int c = idx >> 6, nn = idx & 63;
    out[(((size_t)(b * 64 + c)) << 16) + n0 + nn] = tile[c][nn];
  }
}

// ---------------- MFMA GEMM 64x64 (mask branch + Wp residual) ----------------
#define EP_BIAS 1
#define EP_RESID 5  // fp32 out_(X) += result + bias + aux(P bf16); writes xbout

template<int EP>
__global__ __launch_bounds__(256) void gemm64m(
    const bhalf* __restrict__ in_, const float* __restrict__ w,
    const float* __restrict__ bias, void* __restrict__ out_,
    const bhalf* __restrict__ aux, bhalf* __restrict__ xbout)
{
  __shared__ bhalf WT[64 * 72];     // W^T, [n][k]
  __shared__ float Cs[64 * 68];     // epilogue transpose buffer
  __shared__ float bias_s[64];
  int t = threadIdx.x;
  #pragma unroll
  for (int i = 0; i < 16; ++i) {
    int idx = i * 256 + t;
    int k = idx >> 6, n = idx & 63;
    WT[n * 72 + k] = f2bf(w[k * 64 + n]);
  }
  if (t < 64) bias_s[t] = bias[t];
  __syncthreads();

  int wv = t >> 6, lane = t & 63;
  int lm = lane & 15, q = lane >> 4;
  size_t row0 = ((size_t)blockIdx.x << 6) + (wv << 4);

  const bhalf* arow = in_ + ((row0 + lm) << 6) + (q << 3);
  bf16x8 a0 = *(const bf16x8*)(arow);
  bf16x8 a1 = *(const bf16x8*)(arow + 32);

  f32x4 acc[4];
  #pragma unroll
  for (int nt = 0; nt < 4; ++nt) {
    const bhalf* bp_ = &WT[(nt * 16 + lm) * 72 + (q << 3)];
    bf16x8 b0 = *(const bf16x8*)(bp_);
    bf16x8 b1 = *(const bf16x8*)(bp_ + 32);
    f32x4 c = {0.f, 0.f, 0.f, 0.f};
    c = __builtin_amdgcn_mfma_f32_16x16x32_bf16(a0, b0, c, 0, 0, 0);
    c = __builtin_amdgcn_mfma_f32_16x16x32_bf16(a1, b1, c, 0, 0, 0);
    acc[nt] = c;
  }
  #pragma unroll
  for (int nt = 0; nt < 4; ++nt)
    #pragma unroll
    for (int r = 0; r < 4; ++r)
      Cs[((wv << 4) + (q << 2) + r) * 68 + (nt << 4) + lm] = acc[nt][r];
  __syncthreads();

  int rr = t >> 2, c0 = (t & 3) << 4;
  size_t grow = ((size_t)blockIdx.x << 6) + rr;
  float v[16];
  #pragma unroll
  for (int j = 0; j < 4; ++j) {
    float4 u = *(const float4*)&Cs[rr * 68 + c0 + 4 * j];
    v[4*j] = u.x; v[4*j+1] = u.y; v[4*j+2] = u.z; v[4*j+3] = u.w;
  }

  if (EP == EP_RESID) {
    float* xr = (float*)out_ + (grow << 6) + c0;
    const bhalf* pr = aux + (grow << 6) + c0;
    uint4 p0 = ((const uint4*)pr)[0], p1 = ((const uint4*)pr)[1];
    float pf[16];
    unpack8(p0, pf); unpack8(p1, pf + 8);
    #pragma unroll
    for (int j = 0; j < 4; ++j) {
      float4* x4 = (float4*)(xr + 4 * j);
      float4 u = *x4;
      u.x += v[4*j]   + bias_s[c0 + 4*j]     + pf[4*j];
      u.y += v[4*j+1] + bias_s[c0 + 4*j + 1] + pf[4*j+1];
      u.z += v[4*j+2] + bias_s[c0 + 4*j + 2] + pf[4*j+2];
      u.w += v[4*j+3] + bias_s[c0 + 4*j + 3] + pf[4*j+3];
      *x4 = u;
      v[4*j] = u.x; v[4*j+1] = u.y; v[4*j+2] = u.z; v[4*j+3] = u.w;
    }
    bhalf* xb = xbout + (grow << 6) + c0;
    ((uint4*)xb)[0] = pack16(v);
    ((uint4*)xb)[1] = pack16(v + 8);
  } else {  // EP_BIAS
    #pragma unroll
    for (int j = 0; j < 16; ++j) v[j] += bias_s[c0 + j];
    bhalf* ob = (bhalf*)out_ + (grow << 6) + c0;
    ((uint4*)ob)[0] = pack16(v);
    ((uint4*)ob)[1] = pack16(v + 8);
  }
}

// ---------------- fused QKV: [131072x64] @ [64x192] ----------------
// Outputs Q, K, V and VG = V * MA.
__global__ __launch_bounds__(256) void qkv_gemm(
    const bhalf* __restrict__ xb, const float* __restrict__ wq,
    const float* __restrict__ wk, const float* __restrict__ wv,
    const bhalf* __restrict__ ma, bhalf* __restrict__ Qb,
    bhalf* __restrict__ Kb, bhalf* __restrict__ Vb, bhalf* __restrict__ VG)
{
  __shared__ bhalf WT[192 * 72];
  __shared__ float Cs[64 * 68];
  int t = threadIdx.x;
  #pragma unroll
  for (int i = 0; i < 48; ++i) {
    int idx = i * 256 + t;
    int n = idx >> 6, k = idx & 63;
    const float* src = (n < 64) ? wq : ((n < 128) ? wk : wv);
    WT[n * 72 + k] = f2bf(src[k * 64 + (n & 63)]);
  }
  __syncthreads();

  int wv_ = t >> 6, lane = t & 63;
  int lm = lane & 15, q = lane >> 4;
  size_t row0 = ((size_t)blockIdx.x << 6) + (wv_ << 4);
  const bhalf* arow = xb + ((row0 + lm) << 6) + (q << 3);
  bf16x8 a0 = *(const bf16x8*)(arow);
  bf16x8 a1 = *(const bf16x8*)(arow + 32);

  f32x4 acc[12];
  #pragma unroll
  for (int nt = 0; nt < 12; ++nt) {
    const bhalf* bp_ = &WT[(nt * 16 + lm) * 72 + (q << 3)];
    bf16x8 b0 = *(const bf16x8*)(bp_);
    bf16x8 b1 = *(const bf16x8*)(bp_ + 32);
    f32x4 c = {0.f, 0.f, 0.f, 0.f};
    c = __builtin_amdgcn_mfma_f32_16x16x32_bf16(a0, b0, c, 0, 0, 0);
    c = __builtin_amdgcn_mfma_f32_16x16x32_bf16(a1, b1, c, 0, 0, 0);
    acc[nt] = c;
  }

  int rr = t >> 2, c0 = (t & 3) << 4;
  size_t grow = ((size_t)blockIdx.x << 6) + rr;
  #pragma unroll
  for (int g = 0; g < 3; ++g) {
    __syncthreads();
    #pragma unroll
    for (int nt = 0; nt < 4; ++nt)
      #pragma unroll
      for (int r = 0; r < 4; ++r)
        Cs[((wv_ << 4) + (q << 2) + r) * 68 + (nt << 4) + lm] = acc[g * 4 + nt][r];
    __syncthreads();
    float v[16];
    #pragma unroll
    for (int j = 0; j < 4; ++j) {
      float4 u = *(const float4*)&Cs[rr * 68 + c0 + 4 * j];
      v[4*j] = u.x; v[4*j+1] = u.y; v[4*j+2] = u.z; v[4*j+3] = u.w;
    }
    bhalf* ob = (g == 0 ? Qb : (g == 1 ? Kb : Vb)) + (grow << 6) + c0;
    ((uint4*)ob)[0] = pack16(v);
    ((uint4*)ob)[1] = pack16(v + 8);
    if (g == 2) {
      const bhalf* mr = ma + (grow << 6) + c0;
      uint4 m0 = ((const uint4*)mr)[0], m1q = ((const uint4*)mr)[1];
      float mf[16];
      unpack8(m0, mf); unpack8(m1q, mf + 8);
      float gv[16];
      #pragma unroll
      for (int j = 0; j < 16; ++j) gv[j] = v[j] * mf[j];
      bhalf* gb = VG + (grow << 6) + c0;
      ((uint4*)gb)[0] = pack16(gv);
      ((uint4*)gb)[1] = pack16(gv + 8);
    }
  }
}

// ---------------- FFN gemm1: [131072x64] @ [64x256], GELU ----------------
__global__ __launch_bounds__(256) void ffn_gemm1(
    const bhalf* __restrict__ in_, const float* __restrict__ w,
    bhalf* __restrict__ out_)
{
  __shared__ bhalf WT[256 * 72];
  __shared__ float Cs[64 * 68];
  int t = threadIdx.x;
  #pragma unroll
  for (int i = 0; i < 64; ++i) {
    int idx = i * 256 + t;
    int n = idx >> 6, k = idx & 63;
    WT[n * 72 + k] = f2bf(w[k * 256 + n]);
  }
  __syncthreads();

  int wv_ = t >> 6, lane = t & 63;
  int lm = lane & 15, q = lane >> 4;
  size_t row0 = ((size_t)blockIdx.x << 6) + (wv_ << 4);
  const bhalf* arow = in_ + ((row0 + lm) << 6) + (q << 3);
  bf16x8 a0 = *(const bf16x8*)(arow);
  bf16x8 a1 = *(const bf16x8*)(arow + 32);

  f32x4 acc[16];
  #pragma unroll
  for (int nt = 0; nt < 16; ++nt) {
    const bhalf* bp_ = &WT[(nt * 16 + lm) * 72 + (q << 3)];
    bf16x8 b0 = *(const bf16x8*)(bp_);
    bf16x8 b1 = *(const bf16x8*)(bp_ + 32);
    f32x4 c = {0.f, 0.f, 0.f, 0.f};
    c = __builtin_amdgcn_mfma_f32_16x16x32_bf16(a0, b0, c, 0, 0, 0);
    c = __builtin_amdgcn_mfma_f32_16x16x32_bf16(a1, b1, c, 0, 0, 0);
    acc[nt] = c;
  }

  int rr = t >> 2, c0 = (t & 3) << 4;
  size_t grow = ((size_t)blockIdx.x << 6) + rr;
  #pragma unroll
  for (int g = 0; g < 4; ++g) {
    __syncthreads();
    #pragma unroll
    for (int nt = 0; nt < 4; ++nt)
      #pragma unroll
      for (int r = 0; r < 4; ++r)
        Cs[((wv_ << 4) + (q << 2) + r) * 68 + (nt << 4) + lm] = acc[g * 4 + nt][r];
    __syncthreads();
    float v[16];
    #pragma unroll
    for (int j = 0; j < 4; ++j) {
      float4 u = *(const float4*)&Cs[rr * 68 + c0 + 4 * j];
      v[4*j]   = gelu_f(u.x); v[4*j+1] = gelu_f(u.y);
      v[4*j+2] = gelu_f(u.z); v[4*j+3] = gelu_f(u.w);
    }
    bhalf* ob = out_ + (grow << 8) + (g << 6) + c0;
    ((uint4*)ob)[0] = pack16(v);
    ((uint4*)ob)[1] = pack16(v + 8);
  }
}

// ---------------- FFN gemm2: [131072x256] @ [256x64], X += ; writes Xb ----------------
__global__ __launch_bounds__(256) void ffn_gemm2(
    const bhalf* __restrict__ in_, const float* __restrict__ w,
    float* __restrict__ X, bhalf* __restrict__ Xb)
{
  __shared__ bhalf WT[64 * 264];    // [n][k], k=0..255
  __shared__ float Cs[64 * 68];
  int t = threadIdx.x;
  #pragma unroll
  for (int i = 0; i < 64; ++i) {
    int idx = i * 256 + t;
    int n = idx & 63, k = idx >> 6;
    WT[n * 264 + k] = f2bf(w[k * 64 + n]);
  }
  __syncthreads();

  int wv_ = t >> 6, lane = t & 63;
  int lm = lane & 15, q = lane >> 4;
  size_t row0 = ((size_t)blockIdx.x << 6) + (wv_ << 4);
  const bhalf* arow = in_ + ((row0 + lm) << 8) + (q << 3);
  bf16x8 a[8];
  #pragma unroll
  for (int ch = 0; ch < 8; ++ch) a[ch] = *(const bf16x8*)(arow + 32 * ch);

  f32x4 acc[4];
  #pragma unroll
  for (int nt = 0; nt < 4; ++nt) {
    const bhalf* bp_ = &WT[(nt * 16 + lm) * 264 + (q << 3)];
    f32x4 c = {0.f, 0.f, 0.f, 0.f};
    #pragma unroll
    for (int ch = 0; ch < 8; ++ch) {
      bf16x8 b = *(const bf16x8*)(bp_ + 32 * ch);
      c = __builtin_amdgcn_mfma_f32_16x16x32_bf16(a[ch], b, c, 0, 0, 0);
    }
    acc[nt] = c;
  }
  #pragma unroll
  for (int nt = 0; nt < 4; ++nt)
    #pragma unroll
    for (int r = 0; r < 4; ++r)
      Cs[((wv_ << 4) + (q << 2) + r) * 68 + (nt << 4) + lm] = acc[nt][r];
  __syncthreads();

  int rr = t >> 2, c0 = (t & 3) << 4;
  size_t grow = ((size_t)blockIdx.x << 6) + rr;
  float v[16];
  #pragma unroll
  for (int j = 0; j < 4; ++j) {
    float4 u = *(const float4*)&Cs[rr * 68 + c0 + 4 * j];
    v[4*j] = u.x; v[4*j+1] = u.y; v[4*j+2] = u.z; v[4*j+3] = u.w;
  }
  float* xr = X + (grow << 6) + c0;
  #pragma unroll
  for (int j = 0; j < 4; ++j) {
    float4* x4 = (float4*)(xr + 4 * j);
    float4 u = *x4;
    u.x += v[4*j]; u.y += v[4*j+1]; u.z += v[4*j+2]; u.w += v[4*j+3];
    *x4 = u;
    v[4*j] = u.x; v[4*j+1] = u.y; v[4*j+2] = u.z; v[4*j+3] = u.w;
  }
  bhalf* xb = Xb + (grow << 6) + c0;
  ((uint4*)xb)[0] = pack16(v);
  ((uint4*)xb)[1] = pack16(v + 8);
}

// ---------------- depthwise conv KxK SAME, NHWC ----------------
// CH channels, 8 per thread. EPI: 0 plain, 1 gelu, 2 mask gate.
template<int KS, int EPI, int CH>
__global__ __launch_bounds__(256) void dwconv(
    const bhalf* __restrict__ in, const float* __restrict__ wt,
    const float* __restrict__ db, const bhalf* __restrict__ m1,
    bhalf* __restrict__ out, int wstride)
{
  const int CB = (CH == 64) ? 6 : 8;    // log2(CH)
  __shared__ float Ws[KS * KS * CH];
  __shared__ float db_s[64];
  int t = threadIdx.x;
  for (int idx = t; idx < KS * KS * CH; idx += 256) {
    int tap = idx >> CB, c = idx & (CH - 1);
    Ws[idx] = wt[tap * wstride + c];
  }
  if (EPI == 2 && t < 64) db_s[t] = db[t];
  __syncthreads();
  size_t gid8 = (size_t)blockIdx.x * 256 + t;   // unit = 8 channels
  int c0 = (int)(gid8 & ((CH >> 3) - 1)) << 3;
  size_t p = gid8 >> (CB - 3);
  int wx = (int)(p & 255), hy = (int)((p >> 8) & 255);
  size_t bb = p >> 16;
  const int R = KS >> 1;
  float acc[8];
  #pragma unroll
  for (int j = 0; j < 8; ++j) acc[j] = 0.0f;
  #pragma unroll
  for (int kh = 0; kh < KS; ++kh) {
    int y = hy + kh - R;
    if ((unsigned)y >= 256u) continue;
    #pragma unroll
    for (int kw = 0; kw < KS; ++kw) {
      int xw = wx + kw - R;
      if ((unsigned)xw >= 256u) continue;
      size_t off = (((bb << 8) + (size_t)y) << 8) + (size_t)xw;
      uint4 u = *(const uint4*)(in + (off << CB) + c0);
      float f[8];
      unpack8(u, f);
      const float* wr = &Ws[(kh * KS + kw) * CH + c0];
      #pragma unroll
      for (int j = 0; j < 8; ++j) acc[j] += f[j] * wr[j];
    }
  }
  float r[8];
  if (EPI == 0) {
    #pragma unroll
    for (int j = 0; j < 8; ++j) r[j] = acc[j];
  } else if (EPI == 1) {
    #pragma unroll
    for (int j = 0; j < 8; ++j) r[j] = gelu_f(acc[j]);
  } else {
    uint4 mu = *(const uint4*)(m1 + (p << CB) + c0);
    float mf[8];
    unpack8(mu, mf);
    #pragma unroll
    for (int j = 0; j < 8; ++j) {
      float am = 1.0f / (1.0f + expf(-(acc[j] + db_s[c0 + j])));
      r[j] = mf[j] * (am + 1.0f);
    }
  }
  uint4 s;
  s.x = pack2bf(r[0], r[1]); s.y = pack2bf(r[2], r[3]);
  s.z = pack2bf(r[4], r[5]); s.w = pack2bf(r[6], r[7]);
  *(uint4*)(out + (p << CB) + c0) = s;
}

// ---------------- channel attention partials ----------------
// 1024 blocks x 128 rows; block stages 64x64 tiles; wave = head.
__global__ __launch_bounds__(256) void attn_partial2(
    const bhalf* __restrict__ Q, const bhalf* __restrict__ K,
    float* __restrict__ S, float* __restrict__ nq, float* __restrict__ nk)
{
  __shared__ bhalf Qs[64 * 64], Ks[64 * 64];
  int t = threadIdx.x;
  int h = t >> 6, lane = t & 63;
  int d = lane & 15, e4 = lane >> 4;
  int b = blockIdx.x >> 9;
  size_t rowbase = (size_t)blockIdx.x << 7;
  float acc[4] = {0.f, 0.f, 0.f, 0.f};
  float qss[4] = {0.f, 0.f, 0.f, 0.f};
  float kss = 0.f;
  for (int st = 0; st < 2; ++st) {
    __syncthreads();
    #pragma unroll
    for (int j = 0; j < 2; ++j) {
      int idx = j * 256 + t;
      int r = idx >> 3, seg = (idx & 7) << 3;
      size_t g = ((rowbase + (st << 6) + r) << 6) + seg;
      *(uint4*)&Qs[r * 64 + seg] = *(const uint4*)(Q + g);
      *(uint4*)&Ks[r * 64 + seg] = *(const uint4*)(K + g);
    }
    __syncthreads();
    #pragma unroll 8
    for (int r = 0; r < 64; ++r) {
      float kv = bf2f(Ks[r * 64 + (h << 4) + d]);
      uint2 qu = *(const uint2*)&Qs[r * 64 + (h << 4) + (e4 << 2)];
      float q0, q1, q2, q3;
      unpack2(qu.x, q0, q1); unpack2(qu.y, q2, q3);
      acc[0] += kv * q0; acc[1] += kv * q1; acc[2] += kv * q2; acc[3] += kv * q3;
      qss[0] += q0 * q0; qss[1] += q1 * q1; qss[2] += q2 * q2; qss[3] += q3 * q3;
      kss += kv * kv;
    }
  }
  float* Sp = S + (((b * 4 + h) * 16 + d) << 4) + (e4 << 2);
  atomicAdd(Sp + 0, acc[0]); atomicAdd(Sp + 1, acc[1]);
  atomicAdd(Sp + 2, acc[2]); atomicAdd(Sp + 3, acc[3]);
  if (d == 0) {
    float* qp = nq + b * 64 + (h << 4) + (e4 << 2);
    atomicAdd(qp + 0, qss[0]); atomicAdd(qp + 1, qss[1]);
    atomicAdd(qp + 2, qss[2]); atomicAdd(qp + 3, qss[3]);
  }
  if (e4 == 0) atomicAdd(nk + b * 64 + (h << 4) + d, kss);
}

// softmax over e of S[d,e]*rescale/(max(||k_d||,eps)*max(||q_e||,eps)); writes TRANSPOSED [b][h][e][d]
__global__ void attn_softmax(const float* __restrict__ S, const float* __restrict__ nq,
                             const float* __restrict__ nk, const float* __restrict__ resc,
                             float* __restrict__ attnT)
{
  int b = blockIdx.x >> 2, h = blockIdx.x & 3;
  int d = threadIdx.x;
  if (d >= 16) return;
  float r = resc[h];
  float nkd = fmaxf(sqrtf(nk[b * 64 + h * 16 + d]), 1e-6f);
  float a[16];
  float m = -1e30f;
  #pragma unroll
  for (int e = 0; e < 16; ++e) {
    float nqe = fmaxf(sqrtf(nq[b * 64 + h * 16 + e]), 1e-6f);
    float v = S[(((b * 4 + h) * 16 + d) << 4) + e] * r / (nkd * nqe);
    a[e] = v;
    m = fmaxf(m, v);
  }
  float sum = 0.f;
  #pragma unroll
  for (int e = 0; e < 16; ++e) { a[e] = expf(a[e] - m); sum += a[e]; }
  float inv = 1.0f / sum;
  #pragma unroll
  for (int e = 0; e < 16; ++e)
    attnT[(((b * 4 + h) * 16 + e) << 4) + d] = a[e] * inv;
}

// o[n, h*16+d] = sum_e attnT[h][e][d] * VG[n, h*16+e]
__global__ __launch_bounds__(256) void attnapply_kernel(
    const bhalf* __restrict__ vg, const float* __restrict__ attnT, bhalf* __restrict__ outO)
{
  __shared__ float As[1024];
  int t = threadIdx.x;
  int b = blockIdx.x >> 8;
  #pragma unroll
  for (int j = 0; j < 4; ++j) As[j * 256 + t] = attnT[b * 1024 + j * 256 + t];
  __syncthreads();
  size_t row = (size_t)blockIdx.x * 256 + t;
  const uint4* gv = (const uint4*)(vg + (row << 6));
  bhalf* orow = outO + (row << 6);
  #pragma unroll
  for (int h = 0; h < 4; ++h) {
    uint4 u0 = gv[2 * h], u1 = gv[2 * h + 1];
    float ve[16];
    unpack8(u0, ve); unpack8(u1, ve + 8);
    float4 oh0 = {0,0,0,0}, oh1 = {0,0,0,0}, oh2 = {0,0,0,0}, oh3 = {0,0,0,0};
    #pragma unroll
    for (int e = 0; e < 16; ++e) {
      const float4* ar = (const float4*)&As[(h * 16 + e) << 4];
      float vv = ve[e];
      float4 a0 = ar[0], a1 = ar[1], a2 = ar[2], a3 = ar[3];
      oh0.x += vv*a0.x; oh0.y += vv*a0.y; oh0.z += vv*a0.z; oh0.w += vv*a0.w;
      oh1.x += vv*a1.x; oh1.y += vv*a1.y; oh1.z += vv*a1.z; oh1.w += vv*a1.w;
      oh2.x += vv*a2.x; oh2.y += vv*a2.y; oh2.z += vv*a2.z; oh2.w += vv*a2.w;
      oh3.x += vv*a3.x; oh3.y += vv*a3.y; oh3.z += vv*a3.z; oh3.w += vv*a3.w;
    }
    uint4 s0, s1;
    s0.x = pack2bf(oh0.x, oh0.y); s0.y = pack2bf(oh0.z, oh0.w);
    s0.z = pack2bf(oh1.x, oh1.y); s0.w = pack2bf(oh1.z, oh1.w);
    s1.x = pack2bf(oh2.x, oh2.y); s1.y = pack2bf(oh2.z, oh2.w);
    s1.z = pack2bf(oh3.x, oh3.y); s1.w = pack2bf(oh3.z, oh3.w);
    ((uint4*)(orow + h * 16))[0] = s0;
    ((uint4*)(orow + h * 16))[1] = s1;
  }
}

// ---------------- LayerNorm over C=64, 4 threads/row ----------------
__global__ __launch_bounds__(256) void ln_kernel(
    const float* __restrict__ x, const float* __restrict__ g,
    const float* __restrict__ bb, bhalf* __restrict__ out)
{
  __shared__ float gs[64], bs[64];
  __shared__ float red1[256], red2[256];
  int t = threadIdx.x;
  if (t < 64) { gs[t] = g[t]; bs[t] = bb[t]; }
  int rr = t >> 2, seg = t & 3;
  size_t row = ((size_t)blockIdx.x << 6) + rr;
  const float4* xv = (const float4*)(x + (row << 6) + (seg << 4));
  float v[16];
  #pragma unroll
  for (int j = 0; j < 4; ++j) {
    float4 u = xv[j];
    v[4*j] = u.x; v[4*j+1] = u.y; v[4*j+2] = u.z; v[4*j+3] = u.w;
  }
  float s1 = 0.f, s2 = 0.f;
  #pragma unroll
  for (int j = 0; j < 16; ++j) { s1 += v[j]; s2 += v[j] * v[j]; }
  red1[t] = s1; red2[t] = s2;
  __syncthreads();
  float fs1 = red1[rr*4] + red1[rr*4+1] + red1[rr*4+2] + red1[rr*4+3];
  float fs2 = red2[rr*4] + red2[rr*4+1] + red2[rr*4+2] + red2[rr*4+3];
  float mu = fs1 * 0.015625f;
  float var = fs2 * 0.015625f - mu * mu;
  float rstd = rsqrtf(var + 1e-5f);
  int c0 = seg << 4;
  float r[16];
  #pragma unroll
  for (int j = 0; j < 16; ++j)
    r[j] = (v[j] - mu) * rstd * gs[c0 + j] + bs[c0 + j];
  bhalf* ob = out + (row << 6) + c0;
  ((uint4*)ob)[0] = pack16(r);
  ((uint4*)ob)[1] = pack16(r + 8);
}

// ---------------- host orchestration ----------------
extern "C" void kernel_launch(void* const* d_in, const int* in_sizes, int n_in,
                              void* d_out, int out_size, void* d_ws, size_t ws_size,
                              hipStream_t stream)
{
  (void)in_sizes; (void)n_in; (void)out_size; (void)ws_size;
  const float* x_in    = (const float*)d_in[0];
  const float* mask_in = (const float*)d_in[1];
  const float* Wq    = (const float*)d_in[2];
  const float* Wk    = (const float*)d_in[3];
  const float* Wv    = (const float*)d_in[4];
  const float* resc  = (const float*)d_in[5];
  const float* Wp    = (const float*)d_in[6];
  const float* bp    = (const float*)d_in[7];
  const float* pe1   = (const float*)d_in[8];
  const float* pe2   = (const float*)d_in[9];
  const float* mm_w1 = (const float*)d_in[10];
  const float* mm_b1 = (const float*)d_in[11];
  const float* mm_w2 = (const float*)d_in[12];
  const float* mm_b2 = (const float*)d_in[13];
  const float* mm_dw = (const float*)d_in[14];
  const float* mm_db = (const float*)d_in[15];
  const float* ln_g  = (const float*)d_in[16];
  const float* ln_b  = (const float*)d_in[17];
  const float* ff_w1 = (const float*)d_in[18];
  const float* ff_dw = (const float*)d_in[19];
  const float* ff_w2 = (const float*)d_in[20];

  const size_t NC = 8388608;  // B*N*C
  char* w = (char*)d_ws;
  float* X  = (float*)w; w += NC * 4;   // residual stream, fp32
  bhalf* Xb = (bhalf*)w; w += NC * 2;   // bf16 mirror of X
  bhalf* M  = (bhalf*)w; w += NC * 2;   // mask NHWC
  bhalf* Qb = (bhalf*)w; w += NC * 2;
  bhalf* Kb = (bhalf*)w; w += NC * 2;
  bhalf* Vb = (bhalf*)w; w += NC * 2;
  bhalf* VG = (bhalf*)w; w += NC * 2;
  bhalf* T1 = (bhalf*)w; w += NC * 2;
  bhalf* T2 = (bhalf*)w; w += NC * 2;
  bhalf* T3 = (bhalf*)w; w += NC * 2;
  bhalf* Pb = (bhalf*)w; w += NC * 2;
  float* Sb    = (float*)w; w += 2048 * 4;
  float* nqb   = (float*)w; w += 128 * 4;
  float* nkb   = (float*)w; w += 128 * 4;
  float* attnT = (float*)w; w += 2048 * 4;
  // FFN 256-ch temps alias dead 64-ch buffers (liveness: QKVG dead after
  // attnapply/RESID; T1,T2,T3,Pb dead after gemm1/RESID/qkv/RESID).
  bhalf* F1 = Qb;   // [131072 x 256] ffn hidden (spans Qb,Kb,Vb,VG)
  bhalf* F2 = T1;   // [131072 x 256] post-dwconv (spans T1,T2,T3,Pb)

  nchw2nhwc<0><<<2048, 256, 0, stream>>>(x_in, X, Xb);
  nchw2nhwc<1><<<2048, 256, 0, stream>>>(mask_in, M, nullptr);

  for (int i = 0; i < 3; ++i) {
    // mask branch: m1 = M@w1+b1 (T1); m2 = m1@w2+b2 (T2); MA (T3)
    gemm64m<EP_BIAS><<<GEMM_GRID, 256, 0, stream>>>(M, mm_w1 + i*4096, mm_b1 + i*64, T1, nullptr, nullptr);
    gemm64m<EP_BIAS><<<GEMM_GRID, 256, 0, stream>>>(T1, mm_w2 + i*4096, mm_b2 + i*64, T2, nullptr, nullptr);
    dwconv<5, 2, 64><<<4096, 256, 0, stream>>>(T2, mm_dw + i*1600, mm_db + i*64, T1, T3, 64);
    // fused QKV (+ gate with MA=T3)
    qkv_gemm<<<GEMM_GRID, 256, 0, stream>>>(Xb, Wq + i*4096, Wk + i*4096, Wv + i*4096, T3, Qb, Kb, Vb, VG);
    // channel attention
    hipMemsetAsync(Sb, 0, (2048 + 128 + 128) * 4, stream);
    attn_partial2<<<1024, 256, 0, stream>>>(Qb, Kb, Sb, nqb, nkb);
    attn_softmax<<<8, 64, 0, stream>>>(Sb, nqb, nkb, resc + i*4, attnT);
    // positional branch on ungated V
    dwconv<3, 1, 64><<<4096, 256, 0, stream>>>(Vb, pe1 + i*576, nullptr, nullptr, T1, 64);
    dwconv<3, 0, 64><<<4096, 256, 0, stream>>>(T1, pe2 + i*576, nullptr, nullptr, Pb, 64);
    // o = attn-apply(VG) -> T2; X += o@Wp + bp + P; refresh Xb
    attnapply_kernel<<<512, 256, 0, stream>>>(VG, attnT, T2);
    gemm64m<EP_RESID><<<GEMM_GRID, 256, 0, stream>>>(T2, Wp + i*4096, bp + i*64, X, Pb, Xb);
    // FFN (full 256 hidden): ln -> gemm1(gelu) -> dw3(gelu) -> gemm2(acc)
    ln_kernel<<<LN_GRID, 256, 0, stream>>>(X, ln_g + i*64, ln_b + i*64, T1);
    ffn_gemm1<<<GEMM_GRID, 256, 0, stream>>>(T1, ff_w1 + i*16384, F1);
    dwconv<3, 1, 256><<<16384, 256, 0, stream>>>(F1, ff_dw + i*2304, nullptr, nullptr, F2, 256);
    ffn_gemm2<<<GEMM_GRID, 256, 0, stream>>>(F2, ff_w2 + i*16384, X, Xb);
  }
  nhwc2nchw<<<2048, 256, 0, stream>>>(X, (float*)d_out);
}

// Round 7
// 1324.699 us; speedup vs baseline: 1.0925x; 1.0925x over previous
//
#include <hip/hip_runtime.h>
#include <math.h>

// HGSA: 3x (mask-guided channel-attention MSA + LN + convFFN) on [2,64,256,256].
// External I/O fp32. Internal activations bf16, residual stream X fp32 (+bf16
// mirror Xb), weights bf16 in LDS.
// R5: MFMA gemms. R6: staged attn tiles, un-chunked FFN, fused QKV.
// R7: (a) attn atomics split 32 ways — R6's 512-blocks-per-address chains
// serialized at ~350ns/atomic = the 83us tail; (b) WT/Cs LDS aliasing in all
// MFMA gemms (WT dead after MFMAs) -> ffn_gemm1 2->4 blocks/CU etc.

typedef unsigned short bhalf;
typedef unsigned int u32;
typedef __attribute__((ext_vector_type(8))) short bf16x8;
typedef __attribute__((ext_vector_type(4))) float f32x4;

#define GEMM_GRID 2048      // 131072 rows / 64 rows per block
#define LN_GRID 2048
#define NSPLIT 32           // attn accumulator copies
#define SCOPY 2304          // floats per copy: 2048 S + 128 nq + 128 nk

__device__ __forceinline__ float bf2f(bhalf b) {
  union { u32 u; float f; } c; c.u = ((u32)b) << 16; return c.f;
}
__device__ __forceinline__ bhalf f2bf(float f) {
  union { float f; u32 u; } c; c.f = f;
  u32 lsb = (c.u >> 16) & 1u;
  c.u += 0x7fffu + lsb;           // round-to-nearest-even
  return (bhalf)(c.u >> 16);
}
__device__ __forceinline__ u32 pack2bf(float a, float b) {
  return (u32)f2bf(a) | ((u32)f2bf(b) << 16);
}
__device__ __forceinline__ void unpack2(u32 p, float& a, float& b) {
  union { u32 u; float f; } c0, c1;
  c0.u = p << 16; c1.u = p & 0xffff0000u;
  a = c0.f; b = c1.f;
}
__device__ __forceinline__ void unpack8(uint4 u, float* f) {
  unpack2(u.x, f[0], f[1]); unpack2(u.y, f[2], f[3]);
  unpack2(u.z, f[4], f[5]); unpack2(u.w, f[6], f[7]);
}
__device__ __forceinline__ float gelu_f(float v) {   // exact gelu
  return 0.5f * v * (1.0f + erff(v * 0.70710678118654752440f));
}
__device__ __forceinline__ uint4 pack16(const float* v) {
  uint4 s;
  s.x = pack2bf(v[0], v[1]); s.y = pack2bf(v[2], v[3]);
  s.z = pack2bf(v[4], v[5]); s.w = pack2bf(v[6], v[7]);
  return s;
}

// ---------------- transposes ----------------
template<int MODE>   // 0: x -> fp32 X AND bf16 Xb.  1: mask -> bf16 only.
__global__ __launch_bounds__(256) void nchw2nhwc(const float* __restrict__ in,
                                                 void* __restrict__ out,
                                                 bhalf* __restrict__ out2) {
  __shared__ float tile[64][65];
  int t = threadIdx.x;
  int b = blockIdx.x >> 10;
  int n0 = (blockIdx.x & 1023) << 6;
  #pragma unroll
  for (int j = 0; j < 16; ++j) {
    int idx = j * 256 + t;
    int c = idx >> 6, nn = idx & 63;
    tile[c][nn] = in[(((size_t)(b * 64 + c)) << 16) + n0 + nn];
  }
  __syncthreads();
  #pragma unroll
  for (int j = 0; j < 16; ++j) {
    int idx = j * 256 + t;
    int nn = idx >> 6, c = idx & 63;
    size_t o = ((((size_t)b << 16) + n0 + nn) << 6) + c;
    float v = tile[c][nn];
    if (MODE == 0) { ((float*)out)[o] = v; out2[o] = f2bf(v); }
    else           { ((bhalf*)out)[o] = f2bf(v); }
  }
}

__global__ __launch_bounds__(256) void nhwc2nchw(const float* __restrict__ in,
                                                 float* __restrict__ out) {
  __shared__ float tile[64][65];
  int t = threadIdx.x;
  int b = blockIdx.x >> 10;
  int n0 = (blockIdx.x & 1023) << 6;
  #pragma unroll
  for (int j = 0; j < 16; ++j) {
    int idx = j * 256 + t;
    int nn = idx >> 6, c = idx & 63;
    tile[c][nn] = in[((((size_t)b << 16) + n0 + nn) << 6) + c];
  }
  __syncthreads();
  #pragma unroll
  for (int j = 0; j < 16; ++j) {
    int idx = j * 256 + t;
    int c = idx >> 6, nn = idx & 63;
    out[(((size_t)(b * 64 + c)) << 16) + n0 + nn] = tile[c][nn];
  }
}

// ---------------- MFMA GEMM 64x64 (mask branch + Wp residual) ----------------
#define EP_BIAS 1
#define EP_RESID 5  // fp32 out_(X) += result + bias + aux(P bf16); writes xbout

template<int EP>
__global__ __launch_bounds__(256) void gemm64m(
    const bhalf* __restrict__ in_, const float* __restrict__ w,
    const float* __restrict__ bias, void* __restrict__ out_,
    const bhalf* __restrict__ aux, bhalf* __restrict__ xbout)
{
  __shared__ __align__(16) char smem[64 * 68 * 4];  // WT (9.2KB) then Cs (17.4KB)
  bhalf* WT = (bhalf*)smem;         // W^T, [n][k] stride 72
  float* Cs = (float*)smem;         // epilogue transpose buffer, stride 68
  __shared__ float bias_s[64];
  int t = threadIdx.x;
  #pragma unroll
  for (int i = 0; i < 16; ++i) {
    int idx = i * 256 + t;
    int k = idx >> 6, n = idx & 63;
    WT[n * 72 + k] = f2bf(w[k * 64 + n]);
  }
  if (t < 64) bias_s[t] = bias[t];
  __syncthreads();

  int wv = t >> 6, lane = t & 63;
  int lm = lane & 15, q = lane >> 4;
  size_t row0 = ((size_t)blockIdx.x << 6) + (wv << 4);

  const bhalf* arow = in_ + ((row0 + lm) << 6) + (q << 3);
  bf16x8 a0 = *(const bf16x8*)(arow);
  bf16x8 a1 = *(const bf16x8*)(arow + 32);

  f32x4 acc[4];
  #pragma unroll
  for (int nt = 0; nt < 4; ++nt) {
    const bhalf* bp_ = &WT[(nt * 16 + lm) * 72 + (q << 3)];
    bf16x8 b0 = *(const bf16x8*)(bp_);
    bf16x8 b1 = *(const bf16x8*)(bp_ + 32);
    f32x4 c = {0.f, 0.f, 0.f, 0.f};
    c = __builtin_amdgcn_mfma_f32_16x16x32_bf16(a0, b0, c, 0, 0, 0);
    c = __builtin_amdgcn_mfma_f32_16x16x32_bf16(a1, b1, c, 0, 0, 0);
    acc[nt] = c;
  }
  __syncthreads();   // all waves done with WT before Cs overwrites it
  #pragma unroll
  for (int nt = 0; nt < 4; ++nt)
    #pragma unroll
    for (int r = 0; r < 4; ++r)
      Cs[((wv << 4) + (q << 2) + r) * 68 + (nt << 4) + lm] = acc[nt][r];
  __syncthreads();

  int rr = t >> 2, c0 = (t & 3) << 4;
  size_t grow = ((size_t)blockIdx.x << 6) + rr;
  float v[16];
  #pragma unroll
  for (int j = 0; j < 4; ++j) {
    float4 u = *(const float4*)&Cs[rr * 68 + c0 + 4 * j];
    v[4*j] = u.x; v[4*j+1] = u.y; v[4*j+2] = u.z; v[4*j+3] = u.w;
  }

  if (EP == EP_RESID) {
    float* xr = (float*)out_ + (grow << 6) + c0;
    const bhalf* pr = aux + (grow << 6) + c0;
    uint4 p0 = ((const uint4*)pr)[0], p1 = ((const uint4*)pr)[1];
    float pf[16];
    unpack8(p0, pf); unpack8(p1, pf + 8);
    #pragma unroll
    for (int j = 0; j < 4; ++j) {
      float4* x4 = (float4*)(xr + 4 * j);
      float4 u = *x4;
      u.x += v[4*j]   + bias_s[c0 + 4*j]     + pf[4*j];
      u.y += v[4*j+1] + bias_s[c0 + 4*j + 1] + pf[4*j+1];
      u.z += v[4*j+2] + bias_s[c0 + 4*j + 2] + pf[4*j+2];
      u.w += v[4*j+3] + bias_s[c0 + 4*j + 3] + pf[4*j+3];
      *x4 = u;
      v[4*j] = u.x; v[4*j+1] = u.y; v[4*j+2] = u.z; v[4*j+3] = u.w;
    }
    bhalf* xb = xbout + (grow << 6) + c0;
    ((uint4*)xb)[0] = pack16(v);
    ((uint4*)xb)[1] = pack16(v + 8);
  } else {  // EP_BIAS
    #pragma unroll
    for (int j = 0; j < 16; ++j) v[j] += bias_s[c0 + j];
    bhalf* ob = (bhalf*)out_ + (grow << 6) + c0;
    ((uint4*)ob)[0] = pack16(v);
    ((uint4*)ob)[1] = pack16(v + 8);
  }
}

// ---------------- fused QKV: [131072x64] @ [64x192] ----------------
__global__ __launch_bounds__(256) void qkv_gemm(
    const bhalf* __restrict__ xb, const float* __restrict__ wq,
    const float* __restrict__ wk, const float* __restrict__ wv,
    const bhalf* __restrict__ ma, bhalf* __restrict__ Qb,
    bhalf* __restrict__ Kb, bhalf* __restrict__ Vb, bhalf* __restrict__ VG)
{
  __shared__ __align__(16) char smem[192 * 72 * 2];  // WT 27.6KB; Cs 17.4KB aliased
  bhalf* WT = (bhalf*)smem;
  float* Cs = (float*)smem;
  int t = threadIdx.x;
  #pragma unroll
  for (int i = 0; i < 48; ++i) {
    int idx = i * 256 + t;
    int n = idx >> 6, k = idx & 63;
    const float* src = (n < 64) ? wq : ((n < 128) ? wk : wv);
    WT[n * 72 + k] = f2bf(src[k * 64 + (n & 63)]);
  }
  __syncthreads();

  int wv_ = t >> 6, lane = t & 63;
  int lm = lane & 15, q = lane >> 4;
  size_t row0 = ((size_t)blockIdx.x << 6) + (wv_ << 4);
  const bhalf* arow = xb + ((row0 + lm) << 6) + (q << 3);
  bf16x8 a0 = *(const bf16x8*)(arow);
  bf16x8 a1 = *(const bf16x8*)(arow + 32);

  f32x4 acc[12];
  #pragma unroll
  for (int nt = 0; nt < 12; ++nt) {
    const bhalf* bp_ = &WT[(nt * 16 + lm) * 72 + (q << 3)];
    bf16x8 b0 = *(const bf16x8*)(bp_);
    bf16x8 b1 = *(const bf16x8*)(bp_ + 32);
    f32x4 c = {0.f, 0.f, 0.f, 0.f};
    c = __builtin_amdgcn_mfma_f32_16x16x32_bf16(a0, b0, c, 0, 0, 0);
    c = __builtin_amdgcn_mfma_f32_16x16x32_bf16(a1, b1, c, 0, 0, 0);
    acc[nt] = c;
  }

  int rr = t >> 2, c0 = (t & 3) << 4;
  size_t grow = ((size_t)blockIdx.x << 6) + rr;
  #pragma unroll
  for (int g = 0; g < 3; ++g) {
    __syncthreads();
    #pragma unroll
    for (int nt = 0; nt < 4; ++nt)
      #pragma unroll
      for (int r = 0; r < 4; ++r)
        Cs[((wv_ << 4) + (q << 2) + r) * 68 + (nt << 4) + lm] = acc[g * 4 + nt][r];
    __syncthreads();
    float v[16];
    #pragma unroll
    for (int j = 0; j < 4; ++j) {
      float4 u = *(const float4*)&Cs[rr * 68 + c0 + 4 * j];
      v[4*j] = u.x; v[4*j+1] = u.y; v[4*j+2] = u.z; v[4*j+3] = u.w;
    }
    bhalf* ob = (g == 0 ? Qb : (g == 1 ? Kb : Vb)) + (grow << 6) + c0;
    ((uint4*)ob)[0] = pack16(v);
    ((uint4*)ob)[1] = pack16(v + 8);
    if (g == 2) {
      const bhalf* mr = ma + (grow << 6) + c0;
      uint4 m0 = ((const uint4*)mr)[0], m1q = ((const uint4*)mr)[1];
      float mf[16];
      unpack8(m0, mf); unpack8(m1q, mf + 8);
      float gv[16];
      #pragma unroll
      for (int j = 0; j < 16; ++j) gv[j] = v[j] * mf[j];
      bhalf* gb = VG + (grow << 6) + c0;
      ((uint4*)gb)[0] = pack16(gv);
      ((uint4*)gb)[1] = pack16(gv + 8);
    }
  }
}

// ---------------- FFN gemm1: [131072x64] @ [64x256], GELU ----------------
__global__ __launch_bounds__(256) void ffn_gemm1(
    const bhalf* __restrict__ in_, const float* __restrict__ w,
    bhalf* __restrict__ out_)
{
  __shared__ __align__(16) char smem[256 * 72 * 2];  // WT 36.9KB; Cs aliased
  bhalf* WT = (bhalf*)smem;
  float* Cs = (float*)smem;
  int t = threadIdx.x;
  #pragma unroll
  for (int i = 0; i < 64; ++i) {
    int idx = i * 256 + t;
    int n = idx >> 6, k = idx & 63;
    WT[n * 72 + k] = f2bf(w[k * 256 + n]);
  }
  __syncthreads();

  int wv_ = t >> 6, lane = t & 63;
  int lm = lane & 15, q = lane >> 4;
  size_t row0 = ((size_t)blockIdx.x << 6) + (wv_ << 4);
  const bhalf* arow = in_ + ((row0 + lm) << 6) + (q << 3);
  bf16x8 a0 = *(const bf16x8*)(arow);
  bf16x8 a1 = *(const bf16x8*)(arow + 32);

  f32x4 acc[16];
  #pragma unroll
  for (int nt = 0; nt < 16; ++nt) {
    const bhalf* bp_ = &WT[(nt * 16 + lm) * 72 + (q << 3)];
    bf16x8 b0 = *(const bf16x8*)(bp_);
    bf16x8 b1 = *(const bf16x8*)(bp_ + 32);
    f32x4 c = {0.f, 0.f, 0.f, 0.f};
    c = __builtin_amdgcn_mfma_f32_16x16x32_bf16(a0, b0, c, 0, 0, 0);
    c = __builtin_amdgcn_mfma_f32_16x16x32_bf16(a1, b1, c, 0, 0, 0);
    acc[nt] = c;
  }

  int rr = t >> 2, c0 = (t & 3) << 4;
  size_t grow = ((size_t)blockIdx.x << 6) + rr;
  #pragma unroll
  for (int g = 0; g < 4; ++g) {
    __syncthreads();
    #pragma unroll
    for (int nt = 0; nt < 4; ++nt)
      #pragma unroll
      for (int r = 0; r < 4; ++r)
        Cs[((wv_ << 4) + (q << 2) + r) * 68 + (nt << 4) + lm] = acc[g * 4 + nt][r];
    __syncthreads();
    float v[16];
    #pragma unroll
    for (int j = 0; j < 4; ++j) {
      float4 u = *(const float4*)&Cs[rr * 68 + c0 + 4 * j];
      v[4*j]   = gelu_f(u.x); v[4*j+1] = gelu_f(u.y);
      v[4*j+2] = gelu_f(u.z); v[4*j+3] = gelu_f(u.w);
    }
    bhalf* ob = out_ + (grow << 8) + (g << 6) + c0;
    ((uint4*)ob)[0] = pack16(v);
    ((uint4*)ob)[1] = pack16(v + 8);
  }
}

// ---------------- FFN gemm2: [131072x256] @ [256x64], X += ; writes Xb ----------------
__global__ __launch_bounds__(256) void ffn_gemm2(
    const bhalf* __restrict__ in_, const float* __restrict__ w,
    float* __restrict__ X, bhalf* __restrict__ Xb)
{
  __shared__ __align__(16) char smem[64 * 264 * 2];  // WT 33.8KB; Cs aliased
  bhalf* WT = (bhalf*)smem;
  float* Cs = (float*)smem;
  int t = threadIdx.x;
  #pragma unroll
  for (int i = 0; i < 64; ++i) {
    int idx = i * 256 + t;
    int n = idx & 63, k = idx >> 6;
    WT[n * 264 + k] = f2bf(w[k * 64 + n]);
  }
  __syncthreads();

  int wv_ = t >> 6, lane = t & 63;
  int lm = lane & 15, q = lane >> 4;
  size_t row0 = ((size_t)blockIdx.x << 6) + (wv_ << 4);
  const bhalf* arow = in_ + ((row0 + lm) << 8) + (q << 3);
  bf16x8 a[8];
  #pragma unroll
  for (int ch = 0; ch < 8; ++ch) a[ch] = *(const bf16x8*)(arow + 32 * ch);

  f32x4 acc[4];
  #pragma unroll
  for (int nt = 0; nt < 4; ++nt) {
    const bhalf* bp_ = &WT[(nt * 16 + lm) * 264 + (q << 3)];
    f32x4 c = {0.f, 0.f, 0.f, 0.f};
    #pragma unroll
    for (int ch = 0; ch < 8; ++ch) {
      bf16x8 b = *(const bf16x8*)(bp_ + 32 * ch);
      c = __builtin_amdgcn_mfma_f32_16x16x32_bf16(a[ch], b, c, 0, 0, 0);
    }
    acc[nt] = c;
  }
  __syncthreads();
  #pragma unroll
  for (int nt = 0; nt < 4; ++nt)
    #pragma unroll
    for (int r = 0; r < 4; ++r)
      Cs[((wv_ << 4) + (q << 2) + r) * 68 + (nt << 4) + lm] = acc[nt][r];
  __syncthreads();

  int rr = t >> 2, c0 = (t & 3) << 4;
  size_t grow = ((size_t)blockIdx.x << 6) + rr;
  float v[16];
  #pragma unroll
  for (int j = 0; j < 4; ++j) {
    float4 u = *(const float4*)&Cs[rr * 68 + c0 + 4 * j];
    v[4*j] = u.x; v[4*j+1] = u.y; v[4*j+2] = u.z; v[4*j+3] = u.w;
  }
  float* xr = X + (grow << 6) + c0;
  #pragma unroll
  for (int j = 0; j < 4; ++j) {
    float4* x4 = (float4*)(xr + 4 * j);
    float4 u = *x4;
    u.x += v[4*j]; u.y += v[4*j+1]; u.z += v[4*j+2]; u.w += v[4*j+3];
    *x4 = u;
    v[4*j] = u.x; v[4*j+1] = u.y; v[4*j+2] = u.z; v[4*j+3] = u.w;
  }
  bhalf* xb = Xb + (grow << 6) + c0;
  ((uint4*)xb)[0] = pack16(v);
  ((uint4*)xb)[1] = pack16(v + 8);
}

// ---------------- depthwise conv KxK SAME, NHWC ----------------
template<int KS, int EPI, int CH>
__global__ __launch_bounds__(256) void dwconv(
    const bhalf* __restrict__ in, const float* __restrict__ wt,
    const float* __restrict__ db, const bhalf* __restrict__ m1,
    bhalf* __restrict__ out, int wstride)
{
  const int CB = (CH == 64) ? 6 : 8;    // log2(CH)
  __shared__ float Ws[KS * KS * CH];
  __shared__ float db_s[64];
  int t = threadIdx.x;
  for (int idx = t; idx < KS * KS * CH; idx += 256) {
    int tap = idx >> CB, c = idx & (CH - 1);
    Ws[idx] = wt[tap * wstride + c];
  }
  if (EPI == 2 && t < 64) db_s[t] = db[t];
  __syncthreads();
  size_t gid8 = (size_t)blockIdx.x * 256 + t;   // unit = 8 channels
  int c0 = (int)(gid8 & ((CH >> 3) - 1)) << 3;
  size_t p = gid8 >> (CB - 3);
  int wx = (int)(p & 255), hy = (int)((p >> 8) & 255);
  size_t bb = p >> 16;
  const int R = KS >> 1;
  float acc[8];
  #pragma unroll
  for (int j = 0; j < 8; ++j) acc[j] = 0.0f;
  #pragma unroll
  for (int kh = 0; kh < KS; ++kh) {
    int y = hy + kh - R;
    if ((unsigned)y >= 256u) continue;
    #pragma unroll
    for (int kw = 0; kw < KS; ++kw) {
      int xw = wx + kw - R;
      if ((unsigned)xw >= 256u) continue;
      size_t off = (((bb << 8) + (size_t)y) << 8) + (size_t)xw;
      uint4 u = *(const uint4*)(in + (off << CB) + c0);
      float f[8];
      unpack8(u, f);
      const float* wr = &Ws[(kh * KS + kw) * CH + c0];
      #pragma unroll
      for (int j = 0; j < 8; ++j) acc[j] += f[j] * wr[j];
    }
  }
  float r[8];
  if (EPI == 0) {
    #pragma unroll
    for (int j = 0; j < 8; ++j) r[j] = acc[j];
  } else if (EPI == 1) {
    #pragma unroll
    for (int j = 0; j < 8; ++j) r[j] = gelu_f(acc[j]);
  } else {
    uint4 mu = *(const uint4*)(m1 + (p << CB) + c0);
    float mf[8];
    unpack8(mu, mf);
    #pragma unroll
    for (int j = 0; j < 8; ++j) {
      float am = 1.0f / (1.0f + expf(-(acc[j] + db_s[c0 + j])));
      r[j] = mf[j] * (am + 1.0f);
    }
  }
  uint4 s;
  s.x = pack2bf(r[0], r[1]); s.y = pack2bf(r[2], r[3]);
  s.z = pack2bf(r[4], r[5]); s.w = pack2bf(r[6], r[7]);
  *(uint4*)(out + (p << CB) + c0) = s;
}

// ---------------- channel attention partials ----------------
// 1024 blocks x 128 rows; block stages 64x64 tiles; wave = head.
// Atomics go to copy (blockIdx & 31): chain/address 512 -> 16 (the R6 tail).
__global__ __launch_bounds__(256) void attn_partial2(
    const bhalf* __restrict__ Q, const bhalf* __restrict__ K,
    float* __restrict__ S)
{
  __shared__ bhalf Qs[64 * 64], Ks[64 * 64];
  int t = threadIdx.x;
  int h = t >> 6, lane = t & 63;
  int d = lane & 15, e4 = lane >> 4;
  int b = blockIdx.x >> 9;
  size_t rowbase = (size_t)blockIdx.x << 7;
  float acc[4] = {0.f, 0.f, 0.f, 0.f};
  float qss[4] = {0.f, 0.f, 0.f, 0.f};
  float kss = 0.f;
  for (int st = 0; st < 2; ++st) {
    __syncthreads();
    #pragma unroll
    for (int j = 0; j < 2; ++j) {
      int idx = j * 256 + t;
      int r = idx >> 3, seg = (idx & 7) << 3;
      size_t g = ((rowbase + (st << 6) + r) << 6) + seg;
      *(uint4*)&Qs[r * 64 + seg] = *(const uint4*)(Q + g);
      *(uint4*)&Ks[r * 64 + seg] = *(const uint4*)(K + g);
    }
    __syncthreads();
    #pragma unroll 8
    for (int r = 0; r < 64; ++r) {
      float kv = bf2f(Ks[r * 64 + (h << 4) + d]);
      uint2 qu = *(const uint2*)&Qs[r * 64 + (h << 4) + (e4 << 2)];
      float q0, q1, q2, q3;
      unpack2(qu.x, q0, q1); unpack2(qu.y, q2, q3);
      acc[0] += kv * q0; acc[1] += kv * q1; acc[2] += kv * q2; acc[3] += kv * q3;
      qss[0] += q0 * q0; qss[1] += q1 * q1; qss[2] += q2 * q2; qss[3] += q3 * q3;
      kss += kv * kv;
    }
  }
  float* Sc = S + (size_t)(blockIdx.x & (NSPLIT - 1)) * SCOPY;
  float* Sp = Sc + ((((b * 4 + h) * 16 + d)) << 4) + (e4 << 2);
  atomicAdd(Sp + 0, acc[0]); atomicAdd(Sp + 1, acc[1]);
  atomicAdd(Sp + 2, acc[2]); atomicAdd(Sp + 3, acc[3]);
  if (d == 0) {
    float* qp = Sc + 2048 + b * 64 + (h << 4) + (e4 << 2);
    atomicAdd(qp + 0, qss[0]); atomicAdd(qp + 1, qss[1]);
    atomicAdd(qp + 2, qss[2]); atomicAdd(qp + 3, qss[3]);
  }
  if (e4 == 0) atomicAdd(Sc + 2176 + b * 64 + (h << 4) + d, kss);
}

// sums NSPLIT copies, then softmax; writes TRANSPOSED attnT [b][h][e][d].
// launch <<<8, 16>>> — one wave, LDS broadcast of nq norms.
__global__ void attn_softmax(const float* __restrict__ S,
                             const float* __restrict__ resc,
                             float* __restrict__ attnT)
{
  __shared__ float nqs[16];
  int b = blockIdx.x >> 2, h = blockIdx.x & 3;
  int d = threadIdx.x;
  float nqsum = 0.f, nksum = 0.f;
  for (int c = 0; c < NSPLIT; ++c) {
    nqsum += S[c * SCOPY + 2048 + b * 64 + h * 16 + d];
    nksum += S[c * SCOPY + 2176 + b * 64 + h * 16 + d];
  }
  nqs[d] = fmaxf(sqrtf(nqsum), 1e-6f);
  __syncthreads();
  float nkd = fmaxf(sqrtf(nksum), 1e-6f);
  float r = resc[h];
  float a[16];
  float4 s4[4] = {{0,0,0,0},{0,0,0,0},{0,0,0,0},{0,0,0,0}};
  for (int c = 0; c < NSPLIT; ++c) {
    const float4* sp = (const float4*)&S[c * SCOPY + (((b * 4 + h) * 16 + d) << 4)];
    #pragma unroll
    for (int j = 0; j < 4; ++j) {
      float4 u = sp[j];
      s4[j].x += u.x; s4[j].y += u.y; s4[j].z += u.z; s4[j].w += u.w;
    }
  }
  float m = -1e30f;
  #pragma unroll
  for (int j = 0; j < 4; ++j) {
    a[4*j]   = s4[j].x * r / (nkd * nqs[4*j]);
    a[4*j+1] = s4[j].y * r / (nkd * nqs[4*j+1]);
    a[4*j+2] = s4[j].z * r / (nkd * nqs[4*j+2]);
    a[4*j+3] = s4[j].w * r / (nkd * nqs[4*j+3]);
  }
  #pragma unroll
  for (int e = 0; e < 16; ++e) m = fmaxf(m, a[e]);
  float sum = 0.f;
  #pragma unroll
  for (int e = 0; e < 16; ++e) { a[e] = expf(a[e] - m); sum += a[e]; }
  float inv = 1.0f / sum;
  #pragma unroll
  for (int e = 0; e < 16; ++e)
    attnT[(((b * 4 + h) * 16 + e) << 4) + d] = a[e] * inv;
}

// o[n, h*16+d] = sum_e attnT[h][e][d] * VG[n, h*16+e]
__global__ __launch_bounds__(256) void attnapply_kernel(
    const bhalf* __restrict__ vg, const float* __restrict__ attnT, bhalf* __restrict__ outO)
{
  __shared__ float As[1024];
  int t = threadIdx.x;
  int b = blockIdx.x >> 8;
  #pragma unroll
  for (int j = 0; j < 4; ++j) As[j * 256 + t] = attnT[b * 1024 + j * 256 + t];
  __syncthreads();
  size_t row = (size_t)blockIdx.x * 256 + t;
  const uint4* gv = (const uint4*)(vg + (row << 6));
  bhalf* orow = outO + (row << 6);
  #pragma unroll
  for (int h = 0; h < 4; ++h) {
    uint4 u0 = gv[2 * h], u1 = gv[2 * h + 1];
    float ve[16];
    unpack8(u0, ve); unpack8(u1, ve + 8);
    float4 oh0 = {0,0,0,0}, oh1 = {0,0,0,0}, oh2 = {0,0,0,0}, oh3 = {0,0,0,0};
    #pragma unroll
    for (int e = 0; e < 16; ++e) {
      const float4* ar = (const float4*)&As[(h * 16 + e) << 4];
      float vv = ve[e];
      float4 a0 = ar[0], a1 = ar[1], a2 = ar[2], a3 = ar[3];
      oh0.x += vv*a0.x; oh0.y += vv*a0.y; oh0.z += vv*a0.z; oh0.w += vv*a0.w;
      oh1.x += vv*a1.x; oh1.y += vv*a1.y; oh1.z += vv*a1.z; oh1.w += vv*a1.w;
      oh2.x += vv*a2.x; oh2.y += vv*a2.y; oh2.z += vv*a2.z; oh2.w += vv*a2.w;
      oh3.x += vv*a3.x; oh3.y += vv*a3.y; oh3.z += vv*a3.z; oh3.w += vv*a3.w;
    }
    uint4 s0, s1;
    s0.x = pack2bf(oh0.x, oh0.y); s0.y = pack2bf(oh0.z, oh0.w);
    s0.z = pack2bf(oh1.x, oh1.y); s0.w = pack2bf(oh1.z, oh1.w);
    s1.x = pack2bf(oh2.x, oh2.y); s1.y = pack2bf(oh2.z, oh2.w);
    s1.z = pack2bf(oh3.x, oh3.y); s1.w = pack2bf(oh3.z, oh3.w);
    ((uint4*)(orow + h * 16))[0] = s0;
    ((uint4*)(orow + h * 16))[1] = s1;
  }
}

// ---------------- LayerNorm over C=64, 4 threads/row ----------------
__global__ __launch_bounds__(256) void ln_kernel(
    const float* __restrict__ x, const float* __restrict__ g,
    const float* __restrict__ bb, bhalf* __restrict__ out)
{
  __shared__ float gs[64], bs[64];
  __shared__ float red1[256], red2[256];
  int t = threadIdx.x;
  if (t < 64) { gs[t] = g[t]; bs[t] = bb[t]; }
  int rr = t >> 2, seg = t & 3;
  size_t row = ((size_t)blockIdx.x << 6) + rr;
  const float4* xv = (const float4*)(x + (row << 6) + (seg << 4));
  float v[16];
  #pragma unroll
  for (int j = 0; j < 4; ++j) {
    float4 u = xv[j];
    v[4*j] = u.x; v[4*j+1] = u.y; v[4*j+2] = u.z; v[4*j+3] = u.w;
  }
  float s1 = 0.f, s2 = 0.f;
  #pragma unroll
  for (int j = 0; j < 16; ++j) { s1 += v[j]; s2 += v[j] * v[j]; }
  red1[t] = s1; red2[t] = s2;
  __syncthreads();
  float fs1 = red1[rr*4] + red1[rr*4+1] + red1[rr*4+2] + red1[rr*4+3];
  float fs2 = red2[rr*4] + red2[rr*4+1] + red2[rr*4+2] + red2[rr*4+3];
  float mu = fs1 * 0.015625f;
  float var = fs2 * 0.015625f - mu * mu;
  float rstd = rsqrtf(var + 1e-5f);
  int c0 = seg << 4;
  float r[16];
  #pragma unroll
  for (int j = 0; j < 16; ++j)
    r[j] = (v[j] - mu) * rstd * gs[c0 + j] + bs[c0 + j];
  bhalf* ob = out + (row << 6) + c0;
  ((uint4*)ob)[0] = pack16(r);
  ((uint4*)ob)[1] = pack16(r + 8);
}

// ---------------- host orchestration ----------------
extern "C" void kernel_launch(void* const* d_in, const int* in_sizes, int n_in,
                              void* d_out, int out_size, void* d_ws, size_t ws_size,
                              hipStream_t stream)
{
  (void)in_sizes; (void)n_in; (void)out_size; (void)ws_size;
  const float* x_in    = (const float*)d_in[0];
  const float* mask_in = (const float*)d_in[1];
  const float* Wq    = (const float*)d_in[2];
  const float* Wk    = (const float*)d_in[3];
  const float* Wv    = (const float*)d_in[4];
  const float* resc  = (const float*)d_in[5];
  const float* Wp    = (const float*)d_in[6];
  const float* bp    = (const float*)d_in[7];
  const float* pe1   = (const float*)d_in[8];
  const float* pe2   = (const float*)d_in[9];
  const float* mm_w1 = (const float*)d_in[10];
  const float* mm_b1 = (const float*)d_in[11];
  const float* mm_w2 = (const float*)d_in[12];
  const float* mm_b2 = (const float*)d_in[13];
  const float* mm_dw = (const float*)d_in[14];
  const float* mm_db = (const float*)d_in[15];
  const float* ln_g  = (const float*)d_in[16];
  const float* ln_b  = (const float*)d_in[17];
  const float* ff_w1 = (const float*)d_in[18];
  const float* ff_dw = (const float*)d_in[19];
  const float* ff_w2 = (const float*)d_in[20];

  const size_t NC = 8388608;  // B*N*C
  char* w = (char*)d_ws;
  float* X  = (float*)w; w += NC * 4;   // residual stream, fp32
  bhalf* Xb = (bhalf*)w; w += NC * 2;   // bf16 mirror of X
  bhalf* M  = (bhalf*)w; w += NC * 2;   // mask NHWC
  bhalf* Qb = (bhalf*)w; w += NC * 2;
  bhalf* Kb = (bhalf*)w; w += NC * 2;
  bhalf* Vb = (bhalf*)w; w += NC * 2;
  bhalf* VG = (bhalf*)w; w += NC * 2;
  bhalf* T1 = (bhalf*)w; w += NC * 2;
  bhalf* T2 = (bhalf*)w; w += NC * 2;
  bhalf* T3 = (bhalf*)w; w += NC * 2;
  bhalf* Pb = (bhalf*)w; w += NC * 2;
  float* Sb    = (float*)w; w += (size_t)NSPLIT * SCOPY * 4;  // split accumulators
  float* attnT = (float*)w; w += 2048 * 4;
  // FFN 256-ch temps alias dead 64-ch buffers.
  bhalf* F1 = Qb;   // [131072 x 256] ffn hidden (spans Qb,Kb,Vb,VG)
  bhalf* F2 = T1;   // [131072 x 256] post-dwconv (spans T1,T2,T3,Pb)

  nchw2nhwc<0><<<2048, 256, 0, stream>>>(x_in, X, Xb);
  nchw2nhwc<1><<<2048, 256, 0, stream>>>(mask_in, M, nullptr);

  for (int i = 0; i < 3; ++i) {
    // mask branch: m1 = M@w1+b1 (T1); m2 = m1@w2+b2 (T2); MA (T3)
    gemm64m<EP_BIAS><<<GEMM_GRID, 256, 0, stream>>>(M, mm_w1 + i*4096, mm_b1 + i*64, T1, nullptr, nullptr);
    gemm64m<EP_BIAS><<<GEMM_GRID, 256, 0, stream>>>(T1, mm_w2 + i*4096, mm_b2 + i*64, T2, nullptr, nullptr);
    dwconv<5, 2, 64><<<4096, 256, 0, stream>>>(T2, mm_dw + i*1600, mm_db + i*64, T1, T3, 64);
    // fused QKV (+ gate with MA=T3)
    qkv_gemm<<<GEMM_GRID, 256, 0, stream>>>(Xb, Wq + i*4096, Wk + i*4096, Wv + i*4096, T3, Qb, Kb, Vb, VG);
    // channel attention
    hipMemsetAsync(Sb, 0, NSPLIT * SCOPY * 4, stream);
    attn_partial2<<<1024, 256, 0, stream>>>(Qb, Kb, Sb);
    attn_softmax<<<8, 16, 0, stream>>>(Sb, resc + i*4, attnT);
    // positional branch on ungated V
    dwconv<3, 1, 64><<<4096, 256, 0, stream>>>(Vb, pe1 + i*576, nullptr, nullptr, T1, 64);
    dwconv<3, 0, 64><<<4096, 256, 0, stream>>>(T1, pe2 + i*576, nullptr, nullptr, Pb, 64);
    // o = attn-apply(VG) -> T2; X += o@Wp + bp + P; refresh Xb
    attnapply_kernel<<<512, 256, 0, stream>>>(VG, attnT, T2);
    gemm64m<EP_RESID><<<GEMM_GRID, 256, 0, stream>>>(T2, Wp + i*4096, bp + i*64, X, Pb, Xb);
    // FFN (full 256 hidden): ln -> gemm1(gelu) -> dw3(gelu) -> gemm2(acc)
    ln_kernel<<<LN_GRID, 256, 0, stream>>>(X, ln_g + i*64, ln_b + i*64, T1);
    ffn_gemm1<<<GEMM_GRID, 256, 0, stream>>>(T1, ff_w1 + i*16384, F1);
    dwconv<3, 1, 256><<<16384, 256, 0, stream>>>(F1, ff_dw + i*2304, nullptr, nullptr, F2, 256);
    ffn_gemm2<<<GEMM_GRID, 256, 0, stream>>>(F2, ff_w2 + i*16384, X, Xb);
  }
  nhwc2nchw<<<2048, 256, 0, stream>>>(X, (float*)d_out);
}

// Round 8
// 1080.643 us; speedup vs baseline: 1.3392x; 1.2258x over previous
//
#include <hip/hip_runtime.h>
#include <math.h>

// HGSA: 3x (mask-guided channel-attention MSA + LN + convFFN) on [2,64,256,256].
// External I/O fp32. Internal activations bf16, residual stream X fp32 (+bf16
// mirror Xb), weights bf16 in LDS.
// R5: MFMA gemms. R6: staged attn, un-chunked FFN, fused QKV. R7: attn atomic
// 32-way split; WT/Cs LDS aliasing. R8: weights pre-transposed to bf16 W^T in
// workspace by prep_weights — R7's ffn_gemm1/qkv staging read w[k*N+n] with
// k per-lane = 64-line scatter/wave (~55us of TA serialization); staging is
// now a linear uint4 copy.

typedef unsigned short bhalf;
typedef unsigned int u32;
typedef __attribute__((ext_vector_type(8))) short bf16x8;
typedef __attribute__((ext_vector_type(4))) float f32x4;

#define GEMM_GRID 2048      // 131072 rows / 64 rows per block
#define LN_GRID 2048
#define NSPLIT 32           // attn accumulator copies
#define SCOPY 2304          // floats per copy: 2048 S + 128 nq + 128 nk
#define WBLK 57344          // bf16 per transformer-block weight blob

__device__ __forceinline__ float bf2f(bhalf b) {
  union { u32 u; float f; } c; c.u = ((u32)b) << 16; return c.f;
}
__device__ __forceinline__ bhalf f2bf(float f) {
  union { float f; u32 u; } c; c.f = f;
  u32 lsb = (c.u >> 16) & 1u;
  c.u += 0x7fffu + lsb;           // round-to-nearest-even
  return (bhalf)(c.u >> 16);
}
__device__ __forceinline__ u32 pack2bf(float a, float b) {
  return (u32)f2bf(a) | ((u32)f2bf(b) << 16);
}
__device__ __forceinline__ void unpack2(u32 p, float& a, float& b) {
  union { u32 u; float f; } c0, c1;
  c0.u = p << 16; c1.u = p & 0xffff0000u;
  a = c0.f; b = c1.f;
}
__device__ __forceinline__ void unpack8(uint4 u, float* f) {
  unpack2(u.x, f[0], f[1]); unpack2(u.y, f[2], f[3]);
  unpack2(u.z, f[4], f[5]); unpack2(u.w, f[6], f[7]);
}
__device__ __forceinline__ float gelu_f(float v) {   // exact gelu
  return 0.5f * v * (1.0f + erff(v * 0.70710678118654752440f));
}
__device__ __forceinline__ uint4 pack16(const float* v) {
  uint4 s;
  s.x = pack2bf(v[0], v[1]); s.y = pack2bf(v[2], v[3]);
  s.z = pack2bf(v[4], v[5]); s.w = pack2bf(v[6], v[7]);
  return s;
}

// ---------------- weight pre-transpose (once per launch, ~2us) ----------------
// For each GEMM weight W[K][N]: WTg[n*K + k] = bf16(W[k][n]).
// Per block i: mm1@0, mm2@4096, Q@8192, K@12288, V@16384, P@20480,
//              ff1@24576 ([256][64]), ff2@40960 ([64][256]).
__global__ __launch_bounds__(256) void prep_weights(
    const float* __restrict__ mm_w1, const float* __restrict__ mm_w2,
    const float* __restrict__ Wq, const float* __restrict__ Wk,
    const float* __restrict__ Wv, const float* __restrict__ Wp,
    const float* __restrict__ ff_w1, const float* __restrict__ ff_w2,
    bhalf* __restrict__ out)
{
  int i = blockIdx.x >> 3, slot = blockIdx.x & 7;
  int t = threadIdx.x;
  const float* src; int ksh, N; size_t off;
  switch (slot) {
    case 0:  src = mm_w1 + i*4096;  ksh=6; N=64;  off = 0;     break;
    case 1:  src = mm_w2 + i*4096;  ksh=6; N=64;  off = 4096;  break;
    case 2:  src = Wq + i*4096;     ksh=6; N=64;  off = 8192;  break;
    case 3:  src = Wk + i*4096;     ksh=6; N=64;  off = 12288; break;
    case 4:  src = Wv + i*4096;     ksh=6; N=64;  off = 16384; break;
    case 5:  src = Wp + i*4096;     ksh=6; N=64;  off = 20480; break;
    case 6:  src = ff_w1 + i*16384; ksh=6; N=256; off = 24576; break;
    default: src = ff_w2 + i*16384; ksh=8; N=64;  off = 40960; break;
  }
  bhalf* dst = out + (size_t)i * WBLK + off;
  int sz = N << ksh;
  int kmask = (1 << ksh) - 1;
  for (int idx = t; idx < sz; idx += 256) {
    int n = idx >> ksh, k = idx & kmask;
    dst[idx] = f2bf(src[k * N + n]);
  }
}

// ---------------- transposes ----------------
template<int MODE>   // 0: x -> fp32 X AND bf16 Xb.  1: mask -> bf16 only.
__global__ __launch_bounds__(256) void nchw2nhwc(const float* __restrict__ in,
                                                 void* __restrict__ out,
                                                 bhalf* __restrict__ out2) {
  __shared__ float tile[64][65];
  int t = threadIdx.x;
  int b = blockIdx.x >> 10;
  int n0 = (blockIdx.x & 1023) << 6;
  #pragma unroll
  for (int j = 0; j < 16; ++j) {
    int idx = j * 256 + t;
    int c = idx >> 6, nn = idx & 63;
    tile[c][nn] = in[(((size_t)(b * 64 + c)) << 16) + n0 + nn];
  }
  __syncthreads();
  #pragma unroll
  for (int j = 0; j < 16; ++j) {
    int idx = j * 256 + t;
    int nn = idx >> 6, c = idx & 63;
    size_t o = ((((size_t)b << 16) + n0 + nn) << 6) + c;
    float v = tile[c][nn];
    if (MODE == 0) { ((float*)out)[o] = v; out2[o] = f2bf(v); }
    else           { ((bhalf*)out)[o] = f2bf(v); }
  }
}

__global__ __launch_bounds__(256) void nhwc2nchw(const float* __restrict__ in,
                                                 float* __restrict__ out) {
  __shared__ float tile[64][65];
  int t = threadIdx.x;
  int b = blockIdx.x >> 10;
  int n0 = (blockIdx.x & 1023) << 6;
  #pragma unroll
  for (int j = 0; j < 16; ++j) {
    int idx = j * 256 + t;
    int nn = idx >> 6, c = idx & 63;
    tile[c][nn] = in[((((size_t)b << 16) + n0 + nn) << 6) + c];
  }
  __syncthreads();
  #pragma unroll
  for (int j = 0; j < 16; ++j) {
    int idx = j * 256 + t;
    int c = idx >> 6, nn = idx & 63;
    out[(((size_t)(b * 64 + c)) << 16) + n0 + nn] = tile[c][nn];
  }
}

// ---------------- MFMA GEMM 64x64 (mask branch + Wp residual) ----------------
#define EP_BIAS 1
#define EP_RESID 5  // fp32 out_(X) += result + bias + aux(P bf16); writes xbout

template<int EP>
__global__ __launch_bounds__(256) void gemm64m(
    const bhalf* __restrict__ in_, const bhalf* __restrict__ wt,
    const float* __restrict__ bias, void* __restrict__ out_,
    const bhalf* __restrict__ aux, bhalf* __restrict__ xbout)
{
  __shared__ __align__(16) char smem[64 * 68 * 4];  // WT (9.2KB) then Cs (17.4KB)
  bhalf* WT = (bhalf*)smem;         // W^T, [n][k] stride 72
  float* Cs = (float*)smem;         // epilogue transpose buffer, stride 68
  __shared__ float bias_s[64];
  int t = threadIdx.x;
  {
    const uint4* ws = (const uint4*)wt;
    uint4* wd = (uint4*)WT;
    #pragma unroll
    for (int i = 0; i < 2; ++i) {
      int idx4 = i * 256 + t;               // 512 uint4 total; row = 8 uint4
      int n = idx4 >> 3, q4 = idx4 & 7;
      wd[n * 9 + q4] = ws[idx4];            // LDS row stride 72 bf16 = 9 uint4
    }
    if (t < 64) bias_s[t] = bias[t];
  }
  __syncthreads();

  int wv = t >> 6, lane = t & 63;
  int lm = lane & 15, q = lane >> 4;
  size_t row0 = ((size_t)blockIdx.x << 6) + (wv << 4);

  const bhalf* arow = in_ + ((row0 + lm) << 6) + (q << 3);
  bf16x8 a0 = *(const bf16x8*)(arow);
  bf16x8 a1 = *(const bf16x8*)(arow + 32);

  f32x4 acc[4];
  #pragma unroll
  for (int nt = 0; nt < 4; ++nt) {
    const bhalf* bp_ = &WT[(nt * 16 + lm) * 72 + (q << 3)];
    bf16x8 b0 = *(const bf16x8*)(bp_);
    bf16x8 b1 = *(const bf16x8*)(bp_ + 32);
    f32x4 c = {0.f, 0.f, 0.f, 0.f};
    c = __builtin_amdgcn_mfma_f32_16x16x32_bf16(a0, b0, c, 0, 0, 0);
    c = __builtin_amdgcn_mfma_f32_16x16x32_bf16(a1, b1, c, 0, 0, 0);
    acc[nt] = c;
  }
  __syncthreads();   // all waves done with WT before Cs overwrites it
  #pragma unroll
  for (int nt = 0; nt < 4; ++nt)
    #pragma unroll
    for (int r = 0; r < 4; ++r)
      Cs[((wv << 4) + (q << 2) + r) * 68 + (nt << 4) + lm] = acc[nt][r];
  __syncthreads();

  int rr = t >> 2, c0 = (t & 3) << 4;
  size_t grow = ((size_t)blockIdx.x << 6) + rr;
  float v[16];
  #pragma unroll
  for (int j = 0; j < 4; ++j) {
    float4 u = *(const float4*)&Cs[rr * 68 + c0 + 4 * j];
    v[4*j] = u.x; v[4*j+1] = u.y; v[4*j+2] = u.z; v[4*j+3] = u.w;
  }

  if (EP == EP_RESID) {
    float* xr = (float*)out_ + (grow << 6) + c0;
    const bhalf* pr = aux + (grow << 6) + c0;
    uint4 p0 = ((const uint4*)pr)[0], p1 = ((const uint4*)pr)[1];
    float pf[16];
    unpack8(p0, pf); unpack8(p1, pf + 8);
    #pragma unroll
    for (int j = 0; j < 4; ++j) {
      float4* x4 = (float4*)(xr + 4 * j);
      float4 u = *x4;
      u.x += v[4*j]   + bias_s[c0 + 4*j]     + pf[4*j];
      u.y += v[4*j+1] + bias_s[c0 + 4*j + 1] + pf[4*j+1];
      u.z += v[4*j+2] + bias_s[c0 + 4*j + 2] + pf[4*j+2];
      u.w += v[4*j+3] + bias_s[c0 + 4*j + 3] + pf[4*j+3];
      *x4 = u;
      v[4*j] = u.x; v[4*j+1] = u.y; v[4*j+2] = u.z; v[4*j+3] = u.w;
    }
    bhalf* xb = xbout + (grow << 6) + c0;
    ((uint4*)xb)[0] = pack16(v);
    ((uint4*)xb)[1] = pack16(v + 8);
  } else {  // EP_BIAS
    #pragma unroll
    for (int j = 0; j < 16; ++j) v[j] += bias_s[c0 + j];
    bhalf* ob = (bhalf*)out_ + (grow << 6) + c0;
    ((uint4*)ob)[0] = pack16(v);
    ((uint4*)ob)[1] = pack16(v + 8);
  }
}

// ---------------- fused QKV: [131072x64] @ [64x192] ----------------
// wt = pre-transposed blob, rows 0-63=Q, 64-127=K, 128-191=V.
__global__ __launch_bounds__(256) void qkv_gemm(
    const bhalf* __restrict__ xb, const bhalf* __restrict__ wt,
    const bhalf* __restrict__ ma, bhalf* __restrict__ Qb,
    bhalf* __restrict__ Kb, bhalf* __restrict__ Vb, bhalf* __restrict__ VG)
{
  __shared__ __align__(16) char smem[192 * 72 * 2];  // WT 27.6KB; Cs 17.4KB aliased
  bhalf* WT = (bhalf*)smem;
  float* Cs = (float*)smem;
  int t = threadIdx.x;
  {
    const uint4* ws = (const uint4*)wt;
    uint4* wd = (uint4*)WT;
    #pragma unroll
    for (int i = 0; i < 6; ++i) {
      int idx4 = i * 256 + t;               // 1536 uint4
      int n = idx4 >> 3, q4 = idx4 & 7;
      wd[n * 9 + q4] = ws[idx4];
    }
  }
  __syncthreads();

  int wv_ = t >> 6, lane = t & 63;
  int lm = lane & 15, q = lane >> 4;
  size_t row0 = ((size_t)blockIdx.x << 6) + (wv_ << 4);
  const bhalf* arow = xb + ((row0 + lm) << 6) + (q << 3);
  bf16x8 a0 = *(const bf16x8*)(arow);
  bf16x8 a1 = *(const bf16x8*)(arow + 32);

  f32x4 acc[12];
  #pragma unroll
  for (int nt = 0; nt < 12; ++nt) {
    const bhalf* bp_ = &WT[(nt * 16 + lm) * 72 + (q << 3)];
    bf16x8 b0 = *(const bf16x8*)(bp_);
    bf16x8 b1 = *(const bf16x8*)(bp_ + 32);
    f32x4 c = {0.f, 0.f, 0.f, 0.f};
    c = __builtin_amdgcn_mfma_f32_16x16x32_bf16(a0, b0, c, 0, 0, 0);
    c = __builtin_amdgcn_mfma_f32_16x16x32_bf16(a1, b1, c, 0, 0, 0);
    acc[nt] = c;
  }

  int rr = t >> 2, c0 = (t & 3) << 4;
  size_t grow = ((size_t)blockIdx.x << 6) + rr;
  #pragma unroll
  for (int g = 0; g < 3; ++g) {
    __syncthreads();
    #pragma unroll
    for (int nt = 0; nt < 4; ++nt)
      #pragma unroll
      for (int r = 0; r < 4; ++r)
        Cs[((wv_ << 4) + (q << 2) + r) * 68 + (nt << 4) + lm] = acc[g * 4 + nt][r];
    __syncthreads();
    float v[16];
    #pragma unroll
    for (int j = 0; j < 4; ++j) {
      float4 u = *(const float4*)&Cs[rr * 68 + c0 + 4 * j];
      v[4*j] = u.x; v[4*j+1] = u.y; v[4*j+2] = u.z; v[4*j+3] = u.w;
    }
    bhalf* ob = (g == 0 ? Qb : (g == 1 ? Kb : Vb)) + (grow << 6) + c0;
    ((uint4*)ob)[0] = pack16(v);
    ((uint4*)ob)[1] = pack16(v + 8);
    if (g == 2) {
      const bhalf* mr = ma + (grow << 6) + c0;
      uint4 m0 = ((const uint4*)mr)[0], m1q = ((const uint4*)mr)[1];
      float mf[16];
      unpack8(m0, mf); unpack8(m1q, mf + 8);
      float gv[16];
      #pragma unroll
      for (int j = 0; j < 16; ++j) gv[j] = v[j] * mf[j];
      bhalf* gb = VG + (grow << 6) + c0;
      ((uint4*)gb)[0] = pack16(gv);
      ((uint4*)gb)[1] = pack16(gv + 8);
    }
  }
}

// ---------------- FFN gemm1: [131072x64] @ [64x256], GELU ----------------
__global__ __launch_bounds__(256) void ffn_gemm1(
    const bhalf* __restrict__ in_, const bhalf* __restrict__ wt,
    bhalf* __restrict__ out_)
{
  __shared__ __align__(16) char smem[256 * 72 * 2];  // WT 36.9KB; Cs aliased
  bhalf* WT = (bhalf*)smem;
  float* Cs = (float*)smem;
  int t = threadIdx.x;
  {
    const uint4* ws = (const uint4*)wt;
    uint4* wd = (uint4*)WT;
    #pragma unroll
    for (int i = 0; i < 8; ++i) {
      int idx4 = i * 256 + t;               // 2048 uint4
      int n = idx4 >> 3, q4 = idx4 & 7;
      wd[n * 9 + q4] = ws[idx4];
    }
  }
  __syncthreads();

  int wv_ = t >> 6, lane = t & 63;
  int lm = lane & 15, q = lane >> 4;
  size_t row0 = ((size_t)blockIdx.x << 6) + (wv_ << 4);
  const bhalf* arow = in_ + ((row0 + lm) << 6) + (q << 3);
  bf16x8 a0 = *(const bf16x8*)(arow);
  bf16x8 a1 = *(const bf16x8*)(arow + 32);

  f32x4 acc[16];
  #pragma unroll
  for (int nt = 0; nt < 16; ++nt) {
    const bhalf* bp_ = &WT[(nt * 16 + lm) * 72 + (q << 3)];
    bf16x8 b0 = *(const bf16x8*)(bp_);
    bf16x8 b1 = *(const bf16x8*)(bp_ + 32);
    f32x4 c = {0.f, 0.f, 0.f, 0.f};
    c = __builtin_amdgcn_mfma_f32_16x16x32_bf16(a0, b0, c, 0, 0, 0);
    c = __builtin_amdgcn_mfma_f32_16x16x32_bf16(a1, b1, c, 0, 0, 0);
    acc[nt] = c;
  }

  int rr = t >> 2, c0 = (t & 3) << 4;
  size_t grow = ((size_t)blockIdx.x << 6) + rr;
  #pragma unroll
  for (int g = 0; g < 4; ++g) {
    __syncthreads();
    #pragma unroll
    for (int nt = 0; nt < 4; ++nt)
      #pragma unroll
      for (int r = 0; r < 4; ++r)
        Cs[((wv_ << 4) + (q << 2) + r) * 68 + (nt << 4) + lm] = acc[g * 4 + nt][r];
    __syncthreads();
    float v[16];
    #pragma unroll
    for (int j = 0; j < 4; ++j) {
      float4 u = *(const float4*)&Cs[rr * 68 + c0 + 4 * j];
      v[4*j]   = gelu_f(u.x); v[4*j+1] = gelu_f(u.y);
      v[4*j+2] = gelu_f(u.z); v[4*j+3] = gelu_f(u.w);
    }
    bhalf* ob = out_ + (grow << 8) + (g << 6) + c0;
    ((uint4*)ob)[0] = pack16(v);
    ((uint4*)ob)[1] = pack16(v + 8);
  }
}

// ---------------- FFN gemm2: [131072x256] @ [256x64], X += ; writes Xb ----------------
__global__ __launch_bounds__(256) void ffn_gemm2(
    const bhalf* __restrict__ in_, const bhalf* __restrict__ wt,
    float* __restrict__ X, bhalf* __restrict__ Xb)
{
  __shared__ __align__(16) char smem[64 * 264 * 2];  // WT 33.8KB; Cs aliased
  bhalf* WT = (bhalf*)smem;
  float* Cs = (float*)smem;
  int t = threadIdx.x;
  {
    const uint4* ws = (const uint4*)wt;
    uint4* wd = (uint4*)WT;
    #pragma unroll
    for (int i = 0; i < 8; ++i) {
      int idx4 = i * 256 + t;               // 2048 uint4; row = 32 uint4
      int n = idx4 >> 5, q4 = idx4 & 31;
      wd[n * 33 + q4] = ws[idx4];           // LDS row stride 264 bf16 = 33 uint4
    }
  }
  __syncthreads();

  int wv_ = t >> 6, lane = t & 63;
  int lm = lane & 15, q = lane >> 4;
  size_t row0 = ((size_t)blockIdx.x << 6) + (wv_ << 4);
  const bhalf* arow = in_ + ((row0 + lm) << 8) + (q << 3);
  bf16x8 a[8];
  #pragma unroll
  for (int ch = 0; ch < 8; ++ch) a[ch] = *(const bf16x8*)(arow + 32 * ch);

  f32x4 acc[4];
  #pragma unroll
  for (int nt = 0; nt < 4; ++nt) {
    const bhalf* bp_ = &WT[(nt * 16 + lm) * 264 + (q << 3)];
    f32x4 c = {0.f, 0.f, 0.f, 0.f};
    #pragma unroll
    for (int ch = 0; ch < 8; ++ch) {
      bf16x8 b = *(const bf16x8*)(bp_ + 32 * ch);
      c = __builtin_amdgcn_mfma_f32_16x16x32_bf16(a[ch], b, c, 0, 0, 0);
    }
    acc[nt] = c;
  }
  __syncthreads();
  #pragma unroll
  for (int nt = 0; nt < 4; ++nt)
    #pragma unroll
    for (int r = 0; r < 4; ++r)
      Cs[((wv_ << 4) + (q << 2) + r) * 68 + (nt << 4) + lm] = acc[nt][r];
  __syncthreads();

  int rr = t >> 2, c0 = (t & 3) << 4;
  size_t grow = ((size_t)blockIdx.x << 6) + rr;
  float v[16];
  #pragma unroll
  for (int j = 0; j < 4; ++j) {
    float4 u = *(const float4*)&Cs[rr * 68 + c0 + 4 * j];
    v[4*j] = u.x; v[4*j+1] = u.y; v[4*j+2] = u.z; v[4*j+3] = u.w;
  }
  float* xr = X + (grow << 6) + c0;
  #pragma unroll
  for (int j = 0; j < 4; ++j) {
    float4* x4 = (float4*)(xr + 4 * j);
    float4 u = *x4;
    u.x += v[4*j]; u.y += v[4*j+1]; u.z += v[4*j+2]; u.w += v[4*j+3];
    *x4 = u;
    v[4*j] = u.x; v[4*j+1] = u.y; v[4*j+2] = u.z; v[4*j+3] = u.w;
  }
  bhalf* xb = Xb + (grow << 6) + c0;
  ((uint4*)xb)[0] = pack16(v);
  ((uint4*)xb)[1] = pack16(v + 8);
}

// ---------------- depthwise conv KxK SAME, NHWC ----------------
template<int KS, int EPI, int CH>
__global__ __launch_bounds__(256) void dwconv(
    const bhalf* __restrict__ in, const float* __restrict__ wt,
    const float* __restrict__ db, const bhalf* __restrict__ m1,
    bhalf* __restrict__ out, int wstride)
{
  const int CB = (CH == 64) ? 6 : 8;    // log2(CH)
  __shared__ float Ws[KS * KS * CH];
  __shared__ float db_s[64];
  int t = threadIdx.x;
  for (int idx = t; idx < KS * KS * CH; idx += 256) {
    int tap = idx >> CB, c = idx & (CH - 1);
    Ws[idx] = wt[tap * wstride + c];
  }
  if (EPI == 2 && t < 64) db_s[t] = db[t];
  __syncthreads();
  size_t gid8 = (size_t)blockIdx.x * 256 + t;   // unit = 8 channels
  int c0 = (int)(gid8 & ((CH >> 3) - 1)) << 3;
  size_t p = gid8 >> (CB - 3);
  int wx = (int)(p & 255), hy = (int)((p >> 8) & 255);
  size_t bb = p >> 16;
  const int R = KS >> 1;
  float acc[8];
  #pragma unroll
  for (int j = 0; j < 8; ++j) acc[j] = 0.0f;
  #pragma unroll
  for (int kh = 0; kh < KS; ++kh) {
    int y = hy + kh - R;
    if ((unsigned)y >= 256u) continue;
    #pragma unroll
    for (int kw = 0; kw < KS; ++kw) {
      int xw = wx + kw - R;
      if ((unsigned)xw >= 256u) continue;
      size_t off = (((bb << 8) + (size_t)y) << 8) + (size_t)xw;
      uint4 u = *(const uint4*)(in + (off << CB) + c0);
      float f[8];
      unpack8(u, f);
      const float* wr = &Ws[(kh * KS + kw) * CH + c0];
      #pragma unroll
      for (int j = 0; j < 8; ++j) acc[j] += f[j] * wr[j];
    }
  }
  float r[8];
  if (EPI == 0) {
    #pragma unroll
    for (int j = 0; j < 8; ++j) r[j] = acc[j];
  } else if (EPI == 1) {
    #pragma unroll
    for (int j = 0; j < 8; ++j) r[j] = gelu_f(acc[j]);
  } else {
    uint4 mu = *(const uint4*)(m1 + (p << CB) + c0);
    float mf[8];
    unpack8(mu, mf);
    #pragma unroll
    for (int j = 0; j < 8; ++j) {
      float am = 1.0f / (1.0f + expf(-(acc[j] + db_s[c0 + j])));
      r[j] = mf[j] * (am + 1.0f);
    }
  }
  uint4 s;
  s.x = pack2bf(r[0], r[1]); s.y = pack2bf(r[2], r[3]);
  s.z = pack2bf(r[4], r[5]); s.w = pack2bf(r[6], r[7]);
  *(uint4*)(out + (p << CB) + c0) = s;
}

// ---------------- channel attention partials ----------------
// 1024 blocks x 128 rows; block stages 64x64 tiles; wave = head.
// Atomics go to copy (blockIdx & 31): chain/address 512 -> 16.
__global__ __launch_bounds__(256) void attn_partial2(
    const bhalf* __restrict__ Q, const bhalf* __restrict__ K,
    float* __restrict__ S)
{
  __shared__ bhalf Qs[64 * 64], Ks[64 * 64];
  int t = threadIdx.x;
  int h = t >> 6, lane = t & 63;
  int d = lane & 15, e4 = lane >> 4;
  int b = blockIdx.x >> 9;
  size_t rowbase = (size_t)blockIdx.x << 7;
  float acc[4] = {0.f, 0.f, 0.f, 0.f};
  float qss[4] = {0.f, 0.f, 0.f, 0.f};
  float kss = 0.f;
  for (int st = 0; st < 2; ++st) {
    __syncthreads();
    #pragma unroll
    for (int j = 0; j < 2; ++j) {
      int idx = j * 256 + t;
      int r = idx >> 3, seg = (idx & 7) << 3;
      size_t g = ((rowbase + (st << 6) + r) << 6) + seg;
      *(uint4*)&Qs[r * 64 + seg] = *(const uint4*)(Q + g);
      *(uint4*)&Ks[r * 64 + seg] = *(const uint4*)(K + g);
    }
    __syncthreads();
    #pragma unroll 8
    for (int r = 0; r < 64; ++r) {
      float kv = bf2f(Ks[r * 64 + (h << 4) + d]);
      uint2 qu = *(const uint2*)&Qs[r * 64 + (h << 4) + (e4 << 2)];
      float q0, q1, q2, q3;
      unpack2(qu.x, q0, q1); unpack2(qu.y, q2, q3);
      acc[0] += kv * q0; acc[1] += kv * q1; acc[2] += kv * q2; acc[3] += kv * q3;
      qss[0] += q0 * q0; qss[1] += q1 * q1; qss[2] += q2 * q2; qss[3] += q3 * q3;
      kss += kv * kv;
    }
  }
  float* Sc = S + (size_t)(blockIdx.x & (NSPLIT - 1)) * SCOPY;
  float* Sp = Sc + ((((b * 4 + h) * 16 + d)) << 4) + (e4 << 2);
  atomicAdd(Sp + 0, acc[0]); atomicAdd(Sp + 1, acc[1]);
  atomicAdd(Sp + 2, acc[2]); atomicAdd(Sp + 3, acc[3]);
  if (d == 0) {
    float* qp = Sc + 2048 + b * 64 + (h << 4) + (e4 << 2);
    atomicAdd(qp + 0, qss[0]); atomicAdd(qp + 1, qss[1]);
    atomicAdd(qp + 2, qss[2]); atomicAdd(qp + 3, qss[3]);
  }
  if (e4 == 0) atomicAdd(Sc + 2176 + b * 64 + (h << 4) + d, kss);
}

// sums NSPLIT copies, then softmax; writes TRANSPOSED attnT [b][h][e][d].
__global__ void attn_softmax(const float* __restrict__ S,
                             const float* __restrict__ resc,
                             float* __restrict__ attnT)
{
  __shared__ float nqs[16];
  int b = blockIdx.x >> 2, h = blockIdx.x & 3;
  int d = threadIdx.x;
  float nqsum = 0.f, nksum = 0.f;
  for (int c = 0; c < NSPLIT; ++c) {
    nqsum += S[c * SCOPY + 2048 + b * 64 + h * 16 + d];
    nksum += S[c * SCOPY + 2176 + b * 64 + h * 16 + d];
  }
  nqs[d] = fmaxf(sqrtf(nqsum), 1e-6f);
  __syncthreads();
  float nkd = fmaxf(sqrtf(nksum), 1e-6f);
  float r = resc[h];
  float a[16];
  float4 s4[4] = {{0,0,0,0},{0,0,0,0},{0,0,0,0},{0,0,0,0}};
  for (int c = 0; c < NSPLIT; ++c) {
    const float4* sp = (const float4*)&S[c * SCOPY + (((b * 4 + h) * 16 + d) << 4)];
    #pragma unroll
    for (int j = 0; j < 4; ++j) {
      float4 u = sp[j];
      s4[j].x += u.x; s4[j].y += u.y; s4[j].z += u.z; s4[j].w += u.w;
    }
  }
  float m = -1e30f;
  #pragma unroll
  for (int j = 0; j < 4; ++j) {
    a[4*j]   = s4[j].x * r / (nkd * nqs[4*j]);
    a[4*j+1] = s4[j].y * r / (nkd * nqs[4*j+1]);
    a[4*j+2] = s4[j].z * r / (nkd * nqs[4*j+2]);
    a[4*j+3] = s4[j].w * r / (nkd * nqs[4*j+3]);
  }
  #pragma unroll
  for (int e = 0; e < 16; ++e) m = fmaxf(m, a[e]);
  float sum = 0.f;
  #pragma unroll
  for (int e = 0; e < 16; ++e) { a[e] = expf(a[e] - m); sum += a[e]; }
  float inv = 1.0f / sum;
  #pragma unroll
  for (int e = 0; e < 16; ++e)
    attnT[(((b * 4 + h) * 16 + e) << 4) + d] = a[e] * inv;
}

// o[n, h*16+d] = sum_e attnT[h][e][d] * VG[n, h*16+e]
__global__ __launch_bounds__(256) void attnapply_kernel(
    const bhalf* __restrict__ vg, const float* __restrict__ attnT, bhalf* __restrict__ outO)
{
  __shared__ float As[1024];
  int t = threadIdx.x;
  int b = blockIdx.x >> 8;
  #pragma unroll
  for (int j = 0; j < 4; ++j) As[j * 256 + t] = attnT[b * 1024 + j * 256 + t];
  __syncthreads();
  size_t row = (size_t)blockIdx.x * 256 + t;
  const uint4* gv = (const uint4*)(vg + (row << 6));
  bhalf* orow = outO + (row << 6);
  #pragma unroll
  for (int h = 0; h < 4; ++h) {
    uint4 u0 = gv[2 * h], u1 = gv[2 * h + 1];
    float ve[16];
    unpack8(u0, ve); unpack8(u1, ve + 8);
    float4 oh0 = {0,0,0,0}, oh1 = {0,0,0,0}, oh2 = {0,0,0,0}, oh3 = {0,0,0,0};
    #pragma unroll
    for (int e = 0; e < 16; ++e) {
      const float4* ar = (const float4*)&As[(h * 16 + e) << 4];
      float vv = ve[e];
      float4 a0 = ar[0], a1 = ar[1], a2 = ar[2], a3 = ar[3];
      oh0.x += vv*a0.x; oh0.y += vv*a0.y; oh0.z += vv*a0.z; oh0.w += vv*a0.w;
      oh1.x += vv*a1.x; oh1.y += vv*a1.y; oh1.z += vv*a1.z; oh1.w += vv*a1.w;
      oh2.x += vv*a2.x; oh2.y += vv*a2.y; oh2.z += vv*a2.z; oh2.w += vv*a2.w;
      oh3.x += vv*a3.x; oh3.y += vv*a3.y; oh3.z += vv*a3.z; oh3.w += vv*a3.w;
    }
    uint4 s0, s1;
    s0.x = pack2bf(oh0.x, oh0.y); s0.y = pack2bf(oh0.z, oh0.w);
    s0.z = pack2bf(oh1.x, oh1.y); s0.w = pack2bf(oh1.z, oh1.w);
    s1.x = pack2bf(oh2.x, oh2.y); s1.y = pack2bf(oh2.z, oh2.w);
    s1.z = pack2bf(oh3.x, oh3.y); s1.w = pack2bf(oh3.z, oh3.w);
    ((uint4*)(orow + h * 16))[0] = s0;
    ((uint4*)(orow + h * 16))[1] = s1;
  }
}

// ---------------- LayerNorm over C=64, 4 threads/row ----------------
__global__ __launch_bounds__(256) void ln_kernel(
    const float* __restrict__ x, const float* __restrict__ g,
    const float* __restrict__ bb, bhalf* __restrict__ out)
{
  __shared__ float gs[64], bs[64];
  __shared__ float red1[256], red2[256];
  int t = threadIdx.x;
  if (t < 64) { gs[t] = g[t]; bs[t] = bb[t]; }
  int rr = t >> 2, seg = t & 3;
  size_t row = ((size_t)blockIdx.x << 6) + rr;
  const float4* xv = (const float4*)(x + (row << 6) + (seg << 4));
  float v[16];
  #pragma unroll
  for (int j = 0; j < 4; ++j) {
    float4 u = xv[j];
    v[4*j] = u.x; v[4*j+1] = u.y; v[4*j+2] = u.z; v[4*j+3] = u.w;
  }
  float s1 = 0.f, s2 = 0.f;
  #pragma unroll
  for (int j = 0; j < 16; ++j) { s1 += v[j]; s2 += v[j] * v[j]; }
  red1[t] = s1; red2[t] = s2;
  __syncthreads();
  float fs1 = red1[rr*4] + red1[rr*4+1] + red1[rr*4+2] + red1[rr*4+3];
  float fs2 = red2[rr*4] + red2[rr*4+1] + red2[rr*4+2] + red2[rr*4+3];
  float mu = fs1 * 0.015625f;
  float var = fs2 * 0.015625f - mu * mu;
  float rstd = rsqrtf(var + 1e-5f);
  int c0 = seg << 4;
  float r[16];
  #pragma unroll
  for (int j = 0; j < 16; ++j)
    r[j] = (v[j] - mu) * rstd * gs[c0 + j] + bs[c0 + j];
  bhalf* ob = out + (row << 6) + c0;
  ((uint4*)ob)[0] = pack16(r);
  ((uint4*)ob)[1] = pack16(r + 8);
}

// ---------------- host orchestration ----------------
extern "C" void kernel_launch(void* const* d_in, const int* in_sizes, int n_in,
                              void* d_out, int out_size, void* d_ws, size_t ws_size,
                              hipStream_t stream)
{
  (void)in_sizes; (void)n_in; (void)out_size; (void)ws_size;
  const float* x_in    = (const float*)d_in[0];
  const float* mask_in = (const float*)d_in[1];
  const float* Wq    = (const float*)d_in[2];
  const float* Wk    = (const float*)d_in[3];
  const float* Wv    = (const float*)d_in[4];
  const float* resc  = (const float*)d_in[5];
  const float* Wp    = (const float*)d_in[6];
  const float* bp    = (const float*)d_in[7];
  const float* pe1   = (const float*)d_in[8];
  const float* pe2   = (const float*)d_in[9];
  const float* mm_w1 = (const float*)d_in[10];
  const float* mm_b1 = (const float*)d_in[11];
  const float* mm_w2 = (const float*)d_in[12];
  const float* mm_b2 = (const float*)d_in[13];
  const float* mm_dw = (const float*)d_in[14];
  const float* mm_db = (const float*)d_in[15];
  const float* ln_g  = (const float*)d_in[16];
  const float* ln_b  = (const float*)d_in[17];
  const float* ff_w1 = (const float*)d_in[18];
  const float* ff_dw = (const float*)d_in[19];
  const float* ff_w2 = (const float*)d_in[20];

  const size_t NC = 8388608;  // B*N*C
  char* w = (char*)d_ws;
  float* X  = (float*)w; w += NC * 4;   // residual stream, fp32
  bhalf* Xb = (bhalf*)w; w += NC * 2;   // bf16 mirror of X
  bhalf* M  = (bhalf*)w; w += NC * 2;   // mask NHWC
  bhalf* Qb = (bhalf*)w; w += NC * 2;
  bhalf* Kb = (bhalf*)w; w += NC * 2;
  bhalf* Vb = (bhalf*)w; w += NC * 2;
  bhalf* VG = (bhalf*)w; w += NC * 2;
  bhalf* T1 = (bhalf*)w; w += NC * 2;
  bhalf* T2 = (bhalf*)w; w += NC * 2;
  bhalf* T3 = (bhalf*)w; w += NC * 2;
  bhalf* Pb = (bhalf*)w; w += NC * 2;
  float* Sb    = (float*)w; w += (size_t)NSPLIT * SCOPY * 4;  // split accumulators
  float* attnT = (float*)w; w += 2048 * 4;
  bhalf* WTg   = (bhalf*)w; w += (size_t)3 * WBLK * 2;        // pre-transposed weights
  // FFN 256-ch temps alias dead 64-ch buffers.
  bhalf* F1 = Qb;   // [131072 x 256] ffn hidden (spans Qb,Kb,Vb,VG)
  bhalf* F2 = T1;   // [131072 x 256] post-dwconv (spans T1,T2,T3,Pb)

  prep_weights<<<24, 256, 0, stream>>>(mm_w1, mm_w2, Wq, Wk, Wv, Wp, ff_w1, ff_w2, WTg);
  nchw2nhwc<0><<<2048, 256, 0, stream>>>(x_in, X, Xb);
  nchw2nhwc<1><<<2048, 256, 0, stream>>>(mask_in, M, nullptr);

  for (int i = 0; i < 3; ++i) {
    const bhalf* wb = WTg + (size_t)i * WBLK;
    // mask branch: m1 = M@w1+b1 (T1); m2 = m1@w2+b2 (T2); MA (T3)
    gemm64m<EP_BIAS><<<GEMM_GRID, 256, 0, stream>>>(M, wb + 0, mm_b1 + i*64, T1, nullptr, nullptr);
    gemm64m<EP_BIAS><<<GEMM_GRID, 256, 0, stream>>>(T1, wb + 4096, mm_b2 + i*64, T2, nullptr, nullptr);
    dwconv<5, 2, 64><<<4096, 256, 0, stream>>>(T2, mm_dw + i*1600, mm_db + i*64, T1, T3, 64);
    // fused QKV (+ gate with MA=T3)
    qkv_gemm<<<GEMM_GRID, 256, 0, stream>>>(Xb, wb + 8192, T3, Qb, Kb, Vb, VG);
    // channel attention
    hipMemsetAsync(Sb, 0, NSPLIT * SCOPY * 4, stream);
    attn_partial2<<<1024, 256, 0, stream>>>(Qb, Kb, Sb);
    attn_softmax<<<8, 16, 0, stream>>>(Sb, resc + i*4, attnT);
    // positional branch on ungated V
    dwconv<3, 1, 64><<<4096, 256, 0, stream>>>(Vb, pe1 + i*576, nullptr, nullptr, T1, 64);
    dwconv<3, 0, 64><<<4096, 256, 0, stream>>>(T1, pe2 + i*576, nullptr, nullptr, Pb, 64);
    // o = attn-apply(VG) -> T2; X += o@Wp + bp + P; refresh Xb
    attnapply_kernel<<<512, 256, 0, stream>>>(VG, attnT, T2);
    gemm64m<EP_RESID><<<GEMM_GRID, 256, 0, stream>>>(T2, wb + 20480, bp + i*64, X, Pb, Xb);
    // FFN (full 256 hidden): ln -> gemm1(gelu) -> dw3(gelu) -> gemm2(acc)
    ln_kernel<<<LN_GRID, 256, 0, stream>>>(X, ln_g + i*64, ln_b + i*64, T1);
    ffn_gemm1<<<GEMM_GRID, 256, 0, stream>>>(T1, wb + 24576, F1);
    dwconv<3, 1, 256><<<16384, 256, 0, stream>>>(F1, ff_dw + i*2304, nullptr, nullptr, F2, 256);
    ffn_gemm2<<<GEMM_GRID, 256, 0, stream>>>(F2, wb + 40960, X, Xb);
  }
  nhwc2nchw<<<2048, 256, 0, stream>>>(X, (float*)d_out);
}